// Round 3
// baseline (399.766 us; speedup 1.0000x reference)
//
#include <hip/hip_runtime.h>
#include <cstddef>

typedef __attribute__((ext_vector_type(8))) short short8;
typedef __attribute__((ext_vector_type(4))) float f32x4;

#define B_SZ   512
#define H_SZ   512
#define E_SZ   300
#define LC_SZ  100
#define O_SZ   2004
#define HK     1344     // head K padded (real 1324 = 512 h0 + 300 emb + 512 ans)
#define NK     51200    // annot flat K (100*512)
#define AWK    52524    // attn_W row stride (f32 source)
#define XK     1840     // xm row stride (real 1836)
#define GIK    1328     // GRU-input K padded (real 1324)
#define NSLICE_A 80     // annot split-K slices (640 K each, 10 iters)
#define NSLICE_H 7      // head  split-K slices (192 K each, 3 iters)
#define NSLICE   87
#define ACHUNK 640
#define HCHUNK 192

__device__ __forceinline__ unsigned short f2bf(float f) {
    union { float f; unsigned u; } x; x.f = f;
    unsigned r = x.u + 0x7FFFu + ((x.u >> 16) & 1u);
    return (unsigned short)(r >> 16);
}
__device__ __forceinline__ unsigned pk2(float lo, float hi) {
    return (unsigned)f2bf(lo) | ((unsigned)f2bf(hi) << 16);
}

// ---------------------------------------------------------------------------
// Convert small weights f32 -> bf16, rows padded, pads = 0.
// segs: W_ih, W_hh, mlp_W, out_W, zt_W1, zt_W2   (attn_W handled inline)
// ---------------------------------------------------------------------------
__global__ __launch_bounds__(256) void cvt_weights(
    const float* s_wih, const float* s_whh, const float* s_mlp,
    const float* s_out, const float* s_zt1, const float* s_zt2,
    unsigned short* d_wih, unsigned short* d_whh, unsigned short* d_mlp,
    unsigned short* d_out, unsigned short* d_zt1, unsigned short* d_zt2)
{
    const int cum[6]   = {996, 1380, 1840, 2341, 3261, 3517};
    const int Ks[6]    = {1324, 512, 1836, 512, 1836, 1024};
    const int ldd[6]   = {1328, 512, 1840, 512, 1840, 1024};
    const int elems[6] = {2039808, 786432, 942080, 1026048, 1884160, 524288};
    int blk = blockIdx.x;
    int seg = 0;
    while (seg < 5 && blk >= cum[seg]) seg++;
    int base = (seg == 0) ? 0 : cum[seg - 1];
    const float* src = seg == 0 ? s_wih : seg == 1 ? s_whh : seg == 2 ? s_mlp :
                       seg == 3 ? s_out : seg == 4 ? s_zt1 : s_zt2;
    unsigned short* dst = seg==0?d_wih:seg==1?d_whh:seg==2?d_mlp:
                          seg==3?d_out:seg==4?d_zt1:d_zt2;
    int K = Ks[seg], L = ldd[seg];
    int idx = (blk - base) * 2048 + threadIdx.x * 8;
    if (idx >= elems[seg]) return;
    int row = idx / L;
    int col = idx - row * L;
    unsigned short tmp[8];
    const float* sp = src + (size_t)row * K + col;
    if (col + 8 <= K) {
        float4 a = *(const float4*)sp;
        float4 b = *(const float4*)(sp + 4);
        tmp[0]=f2bf(a.x); tmp[1]=f2bf(a.y); tmp[2]=f2bf(a.z); tmp[3]=f2bf(a.w);
        tmp[4]=f2bf(b.x); tmp[5]=f2bf(b.y); tmp[6]=f2bf(b.z); tmp[7]=f2bf(b.w);
    } else {
        for (int j = 0; j < 8; ++j) {
            int c = col + j;
            tmp[j] = (c < K) ? f2bf(src[(size_t)row * K + c]) : (unsigned short)0;
        }
    }
    *(int4*)(dst + (size_t)row * L + col) = *(int4*)tmp;
}

// ---------------------------------------------------------------------------
// Build bf16 head matrix Ahead[512][1344] = [h0|emb|ans|pad]; also writes
// ans/emb/pad into xm_bf (c_t and h_new slots filled later).
// ---------------------------------------------------------------------------
__global__ __launch_bounds__(256) void build_head(
    const int* __restrict__ input, const int* __restrict__ input_d,
    const float* __restrict__ h0, const float* __restrict__ ans,
    const float* __restrict__ emb_w, const float* __restrict__ emb_d_w,
    unsigned short* __restrict__ Ahead, unsigned short* __restrict__ xm_bf)
{
    int idx = blockIdx.x * 256 + threadIdx.x;      // 512 * 1344
    if (idx >= B_SZ * HK) return;
    int b = idx / HK, c = idx - b * HK;
    unsigned short h = 0;
    if (c < 512) {
        h = f2bf(h0[(size_t)b * 512 + c]);
    } else if (c < 812) {
        int e = c - 512;
        int tok = input[b];
        float v;
        if (tok > 2003) {
            int di = tok - 2004;
            di = min(max(di, 0), LC_SZ - 1);
            int dt = input_d[b * LC_SZ + di];
            v = emb_d_w[(size_t)dt * E_SZ + e];
        } else {
            int t = min(max(tok, 0), 2103);
            v = emb_w[(size_t)t * E_SZ + e];
        }
        h = f2bf(v);
        xm_bf[(size_t)b * XK + 1536 + e] = h;
    } else if (c < 1324) {
        int a = c - 812;
        h = f2bf(ans[(size_t)b * 512 + a]);
        xm_bf[(size_t)b * XK + 1024 + a] = h;
    } else {
        if (c < 1328) xm_bf[(size_t)b * XK + 1836 + (c - 1324)] = 0;  // xm pad
    }
    Ahead[(size_t)b * HK + c] = h;
}

// ---------------------------------------------------------------------------
// MFMA micro-step for 64x128 tile: 4 waves as 2(m) x 2(n), wave = 32x64
// ---------------------------------------------------------------------------
__device__ __forceinline__ void mfma_step128(
    unsigned short (*As)[72], unsigned short (*Bs)[72],
    int wm, int wn, int lane, f32x4 acc[2][4])
{
#pragma unroll
    for (int kk = 0; kk < 2; ++kk) {
        short8 a0 = *(const short8*)&As[wm * 32 +      (lane & 15)][kk * 32 + (lane >> 4) * 8];
        short8 a1 = *(const short8*)&As[wm * 32 + 16 + (lane & 15)][kk * 32 + (lane >> 4) * 8];
#pragma unroll
        for (int tt = 0; tt < 4; ++tt) {
            short8 bb = *(const short8*)&Bs[wn * 64 + tt * 16 + (lane & 15)][kk * 32 + (lane >> 4) * 8];
            acc[0][tt] = __builtin_amdgcn_mfma_f32_16x16x32_bf16(a0, bb, acc[0][tt], 0, 0, 0);
            acc[1][tt] = __builtin_amdgcn_mfma_f32_16x16x32_bf16(a1, bb, acc[1][tt], 0, 0, 0);
        }
    }
}

// ---------------------------------------------------------------------------
// Attention GEMM, split-K, single N pass (BN=128 covers N=100).
// Register-prefetched pipeline; attn_W loaded f32 and converted inline.
// z < 80: annot slices (A f32 -> bf16). z >= 80: head slices (A from Ahead).
// ---------------------------------------------------------------------------
__global__ __launch_bounds__(256) void attn_gemm(
    const float* __restrict__ annot, const unsigned short* __restrict__ Ahead,
    const float* __restrict__ Wf, float* __restrict__ partial)
{
    __shared__ unsigned short As[64][72];
    __shared__ unsigned short Bs[128][72];
    const int t = threadIdx.x;
    const int lane = t & 63, w = t >> 6;
    const int wm = w >> 1, wn = w & 1;
    const int bm = blockIdx.x * 64;
    const int z  = blockIdx.y;
    const int srow = t >> 2, scol = (t & 3) * 16;   // A staging: 4 thr/row, 16 cols
    const int brow = t >> 1, bcol = (t & 1) * 32;   // B staging: 2 thr/row, 32 cols
    const bool bv = (brow < LC_SZ);
    f32x4 acc[2][4] = {};
    const int4 zi4 = {0, 0, 0, 0};

    float4 fb[8] = {};

    if (z < NSLICE_A) {
        const int kb = z * ACHUNK;
        float4 fa[4];
        // prefetch it=0
        {
            const float* ap = annot + (size_t)(bm + srow) * NK + kb + scol;
            fa[0] = ((const float4*)ap)[0]; fa[1] = ((const float4*)ap)[1];
            fa[2] = ((const float4*)ap)[2]; fa[3] = ((const float4*)ap)[3];
            if (bv) {
                const float* wp = Wf + (size_t)brow * AWK + 1324 + kb + bcol;
#pragma unroll
                for (int j = 0; j < 8; ++j) fb[j] = ((const float4*)wp)[j];
            }
        }
        for (int it = 0; it < 10; ++it) {
            // pack + store current tile
            int4 va0 = { (int)pk2(fa[0].x, fa[0].y), (int)pk2(fa[0].z, fa[0].w),
                         (int)pk2(fa[1].x, fa[1].y), (int)pk2(fa[1].z, fa[1].w) };
            int4 va1 = { (int)pk2(fa[2].x, fa[2].y), (int)pk2(fa[2].z, fa[2].w),
                         (int)pk2(fa[3].x, fa[3].y), (int)pk2(fa[3].z, fa[3].w) };
            int4 pb0 = { (int)pk2(fb[0].x, fb[0].y), (int)pk2(fb[0].z, fb[0].w),
                         (int)pk2(fb[1].x, fb[1].y), (int)pk2(fb[1].z, fb[1].w) };
            int4 pb1 = { (int)pk2(fb[2].x, fb[2].y), (int)pk2(fb[2].z, fb[2].w),
                         (int)pk2(fb[3].x, fb[3].y), (int)pk2(fb[3].z, fb[3].w) };
            int4 pb2 = { (int)pk2(fb[4].x, fb[4].y), (int)pk2(fb[4].z, fb[4].w),
                         (int)pk2(fb[5].x, fb[5].y), (int)pk2(fb[5].z, fb[5].w) };
            int4 pb3 = { (int)pk2(fb[6].x, fb[6].y), (int)pk2(fb[6].z, fb[6].w),
                         (int)pk2(fb[7].x, fb[7].y), (int)pk2(fb[7].z, fb[7].w) };
            *(int4*)&As[srow][scol]     = va0;
            *(int4*)&As[srow][scol + 8] = va1;
            *(int4*)&Bs[brow][bcol]      = bv ? pb0 : zi4;
            *(int4*)&Bs[brow][bcol + 8]  = bv ? pb1 : zi4;
            *(int4*)&Bs[brow][bcol + 16] = bv ? pb2 : zi4;
            *(int4*)&Bs[brow][bcol + 24] = bv ? pb3 : zi4;
            __syncthreads();
            // prefetch next tile (overlaps MFMA below)
            if (it + 1 < 10) {
                int k0 = kb + (it + 1) * 64;
                const float* ap = annot + (size_t)(bm + srow) * NK + k0 + scol;
                fa[0] = ((const float4*)ap)[0]; fa[1] = ((const float4*)ap)[1];
                fa[2] = ((const float4*)ap)[2]; fa[3] = ((const float4*)ap)[3];
                if (bv) {
                    const float* wp = Wf + (size_t)brow * AWK + 1324 + k0 + bcol;
#pragma unroll
                    for (int j = 0; j < 8; ++j) fb[j] = ((const float4*)wp)[j];
                }
            }
            mfma_step128(As, Bs, wm, wn, lane, acc);
            __syncthreads();
        }
    } else {
        const int kb = (z - NSLICE_A) * HCHUNK;
        int4 ra0, ra1;
        // prefetch it=0
        {
            const unsigned short* ap = Ahead + (size_t)(bm + srow) * HK + kb + scol;
            ra0 = ((const int4*)ap)[0]; ra1 = ((const int4*)ap)[1];
            if (bv) {
                const float* wp = Wf + (size_t)brow * AWK + kb + bcol;
                if (kb + bcol + 32 <= 1324) {
#pragma unroll
                    for (int j = 0; j < 8; ++j) fb[j] = ((const float4*)wp)[j];
                } else {
#pragma unroll
                    for (int e = 0; e < 32; ++e)
                        ((float*)fb)[e] = (kb + bcol + e < 1324) ? wp[e] : 0.0f;
                }
            }
        }
        for (int it = 0; it < 3; ++it) {
            int4 pb0 = { (int)pk2(fb[0].x, fb[0].y), (int)pk2(fb[0].z, fb[0].w),
                         (int)pk2(fb[1].x, fb[1].y), (int)pk2(fb[1].z, fb[1].w) };
            int4 pb1 = { (int)pk2(fb[2].x, fb[2].y), (int)pk2(fb[2].z, fb[2].w),
                         (int)pk2(fb[3].x, fb[3].y), (int)pk2(fb[3].z, fb[3].w) };
            int4 pb2 = { (int)pk2(fb[4].x, fb[4].y), (int)pk2(fb[4].z, fb[4].w),
                         (int)pk2(fb[5].x, fb[5].y), (int)pk2(fb[5].z, fb[5].w) };
            int4 pb3 = { (int)pk2(fb[6].x, fb[6].y), (int)pk2(fb[6].z, fb[6].w),
                         (int)pk2(fb[7].x, fb[7].y), (int)pk2(fb[7].z, fb[7].w) };
            *(int4*)&As[srow][scol]     = ra0;
            *(int4*)&As[srow][scol + 8] = ra1;
            *(int4*)&Bs[brow][bcol]      = bv ? pb0 : zi4;
            *(int4*)&Bs[brow][bcol + 8]  = bv ? pb1 : zi4;
            *(int4*)&Bs[brow][bcol + 16] = bv ? pb2 : zi4;
            *(int4*)&Bs[brow][bcol + 24] = bv ? pb3 : zi4;
            __syncthreads();
            if (it + 1 < 3) {
                int k0 = kb + (it + 1) * 64;
                const unsigned short* ap = Ahead + (size_t)(bm + srow) * HK + k0 + scol;
                ra0 = ((const int4*)ap)[0]; ra1 = ((const int4*)ap)[1];
                if (bv) {
                    const float* wp = Wf + (size_t)brow * AWK + k0 + bcol;
                    if (k0 + bcol + 32 <= 1324) {
#pragma unroll
                        for (int j = 0; j < 8; ++j) fb[j] = ((const float4*)wp)[j];
                    } else {
#pragma unroll
                        for (int e = 0; e < 32; ++e)
                            ((float*)fb)[e] = (k0 + bcol + e < 1324) ? wp[e] : 0.0f;
                    }
                }
            }
            mfma_step128(As, Bs, wm, wn, lane, acc);
            __syncthreads();
        }
    }
#pragma unroll
    for (int tt = 0; tt < 4; ++tt) {
        int n = wn * 64 + tt * 16 + (lane & 15);
        if (n >= LC_SZ) continue;
#pragma unroll
        for (int s = 0; s < 2; ++s) {
#pragma unroll
            for (int r = 0; r < 4; ++r) {
                int m = bm + wm * 32 + s * 16 + (lane >> 4) * 4 + r;
                partial[((size_t)z * B_SZ + m) * LC_SZ + n] = acc[s][tt][r];
            }
        }
    }
}

// ---------------------------------------------------------------------------
// Reduce partials (4 independent accumulators) + tanh + softmax(100)
// ---------------------------------------------------------------------------
__global__ __launch_bounds__(128) void attn_reduce_softmax(
    const float* __restrict__ partial, const float* __restrict__ attn_b,
    float* __restrict__ attn_w_out)
{
    int b = blockIdx.x, tid = threadIdx.x;
    __shared__ float red[128];

    float v = -1e30f;
    float e = 0.0f;
    if (tid < LC_SZ) {
        float s0 = 0.0f, s1 = 0.0f, s2 = 0.0f, s3 = 0.0f;
        const float* pp = partial + (size_t)b * LC_SZ + tid;
        int sp = 0;
        for (; sp + 4 <= NSLICE; sp += 4) {
            s0 += pp[(size_t)(sp    ) * B_SZ * LC_SZ];
            s1 += pp[(size_t)(sp + 1) * B_SZ * LC_SZ];
            s2 += pp[(size_t)(sp + 2) * B_SZ * LC_SZ];
            s3 += pp[(size_t)(sp + 3) * B_SZ * LC_SZ];
        }
        for (; sp < NSLICE; ++sp) s0 += pp[(size_t)sp * B_SZ * LC_SZ];
        v = tanhf(attn_b[tid] + s0 + s1 + s2 + s3);
    }
    red[tid] = v; __syncthreads();
    for (int s = 64; s > 0; s >>= 1) { if (tid < s) red[tid] = fmaxf(red[tid], red[tid + s]); __syncthreads(); }
    float mx = red[0]; __syncthreads();

    if (tid < LC_SZ) e = expf(v - mx);
    red[tid] = e; __syncthreads();
    for (int s = 64; s > 0; s >>= 1) { if (tid < s) red[tid] += red[tid + s]; __syncthreads(); }
    float denom = red[0];

    if (tid < LC_SZ) attn_w_out[b * LC_SZ + tid] = e / denom;
}

// ---------------------------------------------------------------------------
// c_t[b][h] = sum_l w[b][l] * annot[b][l][h]  — grid (b, h-half), high TLP
// ---------------------------------------------------------------------------
__global__ __launch_bounds__(256) void attn_ct(
    const float* __restrict__ attn_w, const float* __restrict__ annot,
    unsigned short* __restrict__ xm_bf)
{
    int b = blockIdx.x;
    int h = blockIdx.y * 256 + threadIdx.x;
    __shared__ float sw[LC_SZ];
    if (threadIdx.x < LC_SZ) sw[threadIdx.x] = attn_w[b * LC_SZ + threadIdx.x];
    __syncthreads();

    const float* ap = annot + (size_t)b * NK + h;
    float a0 = 0.0f, a1 = 0.0f, a2 = 0.0f, a3 = 0.0f;
#pragma unroll
    for (int l = 0; l < LC_SZ; l += 4) {
        a0 += sw[l    ] * ap[(l    ) * 512];
        a1 += sw[l + 1] * ap[(l + 1) * 512];
        a2 += sw[l + 2] * ap[(l + 2) * 512];
        a3 += sw[l + 3] * ap[(l + 3) * 512];
    }
    xm_bf[(size_t)b * XK + 512 + h] = f2bf((a0 + a1) + (a2 + a3));
}

// ---------------------------------------------------------------------------
// Shared 64x64 GEMM core (2x2 waves of 32x32), register-prefetch pipeline
// ---------------------------------------------------------------------------
__device__ __forceinline__ void gemm64_core(
    unsigned short (*As)[72], unsigned short (*Bs)[72],
    const unsigned short* Ablk, long lda,
    const unsigned short* Wblk, long ldw, int nrows,
    int Kpad, f32x4 acc[2][2])
{
    const int t = threadIdx.x;
    const int lane = t & 63, w = t >> 6;
    const int wm = w >> 1, wn = w & 1;
    const int srow = t >> 2, scol = (t & 3) * 16;
    const bool brv = (srow < nrows);
    int4 ra[2], rb[2];
#pragma unroll
    for (int i = 0; i < 2; ++i) {
        int gk = scol + i * 8;
        int4 v = {0, 0, 0, 0};
        if (gk < Kpad) v = *(const int4*)(Ablk + (size_t)srow * lda + gk);
        ra[i] = v;
        int4 u = {0, 0, 0, 0};
        if (gk < Kpad && brv) u = *(const int4*)(Wblk + (size_t)srow * ldw + gk);
        rb[i] = u;
    }
    for (int k0 = 0; k0 < Kpad; k0 += 64) {
        *(int4*)&As[srow][scol]     = ra[0];
        *(int4*)&As[srow][scol + 8] = ra[1];
        *(int4*)&Bs[srow][scol]     = rb[0];
        *(int4*)&Bs[srow][scol + 8] = rb[1];
        __syncthreads();
        if (k0 + 64 < Kpad) {
#pragma unroll
            for (int i = 0; i < 2; ++i) {
                int gk = k0 + 64 + scol + i * 8;
                int4 v = {0, 0, 0, 0};
                if (gk < Kpad) v = *(const int4*)(Ablk + (size_t)srow * lda + gk);
                ra[i] = v;
                int4 u = {0, 0, 0, 0};
                if (gk < Kpad && brv) u = *(const int4*)(Wblk + (size_t)srow * ldw + gk);
                rb[i] = u;
            }
        }
#pragma unroll
        for (int kk = 0; kk < 2; ++kk) {
            short8 a0 = *(const short8*)&As[wm * 32 +      (lane & 15)][kk * 32 + (lane >> 4) * 8];
            short8 a1 = *(const short8*)&As[wm * 32 + 16 + (lane & 15)][kk * 32 + (lane >> 4) * 8];
            short8 b0 = *(const short8*)&Bs[wn * 32 +      (lane & 15)][kk * 32 + (lane >> 4) * 8];
            short8 b1 = *(const short8*)&Bs[wn * 32 + 16 + (lane & 15)][kk * 32 + (lane >> 4) * 8];
            acc[0][0] = __builtin_amdgcn_mfma_f32_16x16x32_bf16(a0, b0, acc[0][0], 0, 0, 0);
            acc[0][1] = __builtin_amdgcn_mfma_f32_16x16x32_bf16(a0, b1, acc[0][1], 0, 0, 0);
            acc[1][0] = __builtin_amdgcn_mfma_f32_16x16x32_bf16(a1, b0, acc[1][0], 0, 0, 0);
            acc[1][1] = __builtin_amdgcn_mfma_f32_16x16x32_bf16(a1, b1, acc[1][1], 0, 0, 0);
        }
        __syncthreads();
    }
}

// ---------------------------------------------------------------------------
// gi = [c_t|ans|emb] @ W_ih^T + b_ih  (bn<24) ; gh = h0 @ W_hh^T + b_hh
// ---------------------------------------------------------------------------
__global__ __launch_bounds__(256) void gigh_gemm(
    const unsigned short* __restrict__ xm, const unsigned short* __restrict__ Ahead,
    const unsigned short* __restrict__ Wih, const unsigned short* __restrict__ Whh,
    const float* __restrict__ bih, const float* __restrict__ bhh,
    float* __restrict__ gi, float* __restrict__ gh)
{
    __shared__ unsigned short As[64][72];
    __shared__ unsigned short Bs[64][72];
    const int t = threadIdx.x;
    const int lane = t & 63, w = t >> 6;
    const int wm = w >> 1, wn = w & 1;
    const int bm = blockIdx.x * 64;
    const unsigned short* Ablk; long lda; const unsigned short* Wblk; long ldw;
    const float* bias; float* C; int Kpad, bn;
    if (blockIdx.y < 24) {
        bn = blockIdx.y * 64;
        Ablk = xm + (size_t)bm * XK + 512; lda = XK;
        Wblk = Wih + (size_t)bn * GIK;     ldw = GIK;
        bias = bih; C = gi; Kpad = GIK;
    } else {
        bn = (blockIdx.y - 24) * 64;
        Ablk = Ahead + (size_t)bm * HK;    lda = HK;
        Wblk = Whh + (size_t)bn * 512;     ldw = 512;
        bias = bhh; C = gh; Kpad = 512;
    }
    f32x4 acc[2][2] = {};
    gemm64_core(As, Bs, Ablk, lda, Wblk, ldw, 64, Kpad, acc);
#pragma unroll
    for (int tt = 0; tt < 2; ++tt) {
        int n = bn + wn * 32 + tt * 16 + (lane & 15);
        float bv = bias[n];
#pragma unroll
        for (int s = 0; s < 2; ++s)
#pragma unroll
            for (int r = 0; r < 4; ++r) {
                int m = bm + wm * 32 + s * 16 + (lane >> 4) * 4 + r;
                C[(size_t)m * 1536 + n] = acc[s][tt][r] + bv;
            }
    }
}

// ---------------------------------------------------------------------------
// GRU elementwise; h_new -> out slots 0/1 (f32) and xm_bf[b][0:512] (bf16)
// ---------------------------------------------------------------------------
__global__ __launch_bounds__(256) void gru_kernel(
    const float* __restrict__ gi, const float* __restrict__ gh,
    const float* __restrict__ h0, unsigned short* __restrict__ xm_bf,
    float* __restrict__ out01)
{
    int idx = blockIdx.x * 256 + threadIdx.x;   // B*H
    int b = idx >> 9, h = idx & 511;
    float ir  = gi[(size_t)b * 1536 + h];
    float iz  = gi[(size_t)b * 1536 + 512 + h];
    float inn = gi[(size_t)b * 1536 + 1024 + h];
    float hr  = gh[(size_t)b * 1536 + h];
    float hz  = gh[(size_t)b * 1536 + 512 + h];
    float hn  = gh[(size_t)b * 1536 + 1024 + h];
    float r = 1.0f / (1.0f + expf(-(ir + hr)));
    float z = 1.0f / (1.0f + expf(-(iz + hz)));
    float n = tanhf(inn + r * hn);
    float hp = h0[idx];
    float hv = (1.0f - z) * n + z * hp;
    xm_bf[(size_t)b * XK + h] = f2bf(hv);
    out01[idx] = hv;
    out01[B_SZ * H_SZ + idx] = hv;
}

// ---------------------------------------------------------------------------
// tail1: N=1536 fused — e_t = xm@mlp_W^T (bf16 out), z1 = tanh(xm@zt_W1^T)
// ---------------------------------------------------------------------------
__global__ __launch_bounds__(256) void tail1_gemm(
    const unsigned short* __restrict__ xm,
    const unsigned short* __restrict__ mlpW, const unsigned short* __restrict__ ztW1,
    const float* __restrict__ mlpb, const float* __restrict__ ztb1,
    unsigned short* __restrict__ et, unsigned short* __restrict__ z1)
{
    __shared__ unsigned short As[64][72];
    __shared__ unsigned short Bs[64][72];
    const int t = threadIdx.x;
    const int lane = t & 63, w = t >> 6;
    const int wm = w >> 1, wn = w & 1;
    const int bm = blockIdx.x * 64;
    const int mlp = blockIdx.y < 8;
    const int bn = mlp ? blockIdx.y * 64 : (blockIdx.y - 8) * 64;
    const unsigned short* Wblk = (mlp ? mlpW : ztW1) + (size_t)bn * XK;
    f32x4 acc[2][2] = {};
    gemm64_core(As, Bs, xm + (size_t)bm * XK, XK, Wblk, XK, 64, XK, acc);
#pragma unroll
    for (int tt = 0; tt < 2; ++tt) {
        int n = bn + wn * 32 + tt * 16 + (lane & 15);
        float bv = mlp ? mlpb[n] : ztb1[n];
#pragma unroll
        for (int s = 0; s < 2; ++s)
#pragma unroll
            for (int r = 0; r < 4; ++r) {
                int m = bm + wm * 32 + s * 16 + (lane >> 4) * 4 + r;
                float v = acc[s][tt][r] + bv;
                if (mlp) et[(size_t)m * 512 + n] = f2bf(v);
                else     z1[(size_t)m * 1024 + n] = f2bf(tanhf(v));
            }
    }
}

// ---------------------------------------------------------------------------
// tail2: fused — lo = e_t@out_W^T (bn<32), z2 = tanh(z1@zt_W2^T)
// ---------------------------------------------------------------------------
__global__ __launch_bounds__(256) void tail2_gemm(
    const unsigned short* __restrict__ et, const unsigned short* __restrict__ z1,
    const unsigned short* __restrict__ outW, const unsigned short* __restrict__ ztW2,
    const float* __restrict__ outb, const float* __restrict__ ztb2,
    float* __restrict__ lo, float* __restrict__ z2)
{
    __shared__ unsigned short As[64][72];
    __shared__ unsigned short Bs[64][72];
    const int t = threadIdx.x;
    const int lane = t & 63, w = t >> 6;
    const int wm = w >> 1, wn = w & 1;
    const int bm = blockIdx.x * 64;
    const int outp = blockIdx.y < 32;
    const int bn = outp ? blockIdx.y * 64 : (blockIdx.y - 32) * 64;
    const unsigned short* Ablk; long lda; const unsigned short* Wblk; long ldw;
    int Kpad, nrows;
    if (outp) {
        Ablk = et + (size_t)bm * 512; lda = 512;
        Wblk = outW + (size_t)bn * 512; ldw = 512;
        Kpad = 512; nrows = min(64, O_SZ - bn);
    } else {
        Ablk = z1 + (size_t)bm * 1024; lda = 1024;
        Wblk = ztW2 + (size_t)bn * 1024; ldw = 1024;
        Kpad = 1024; nrows = 64;
    }
    f32x4 acc[2][2] = {};
    gemm64_core(As, Bs, Ablk, lda, Wblk, ldw, nrows, Kpad, acc);
#pragma unroll
    for (int tt = 0; tt < 2; ++tt) {
        int n = bn + wn * 32 + tt * 16 + (lane & 15);
        if (outp && n >= O_SZ) continue;
        float bv = outp ? outb[n] : ztb2[n];
#pragma unroll
        for (int s = 0; s < 2; ++s)
#pragma unroll
            for (int r = 0; r < 4; ++r) {
                int m = bm + wm * 32 + s * 16 + (lane >> 4) * 4 + r;
                float v = acc[s][tt][r] + bv;
                if (outp) lo[(size_t)m * O_SZ + n] = v;
                else      z2[(size_t)m * 512 + n] = tanhf(v);
            }
    }
}

// ---------------------------------------------------------------------------
// Fused z_t dot + single-pass softmax over lo (row resident in registers)
// ---------------------------------------------------------------------------
__global__ __launch_bounds__(256) void out_softmax(
    const float* __restrict__ lo, const float* __restrict__ attn_w,
    const float* __restrict__ z2, const float* __restrict__ W3,
    const float* __restrict__ b3, float* __restrict__ pt)
{
    int b = blockIdx.x, tid = threadIdx.x;
    __shared__ float red[256];

    // z_t = sigmoid(z2[b] . W3 + b3)
    float a = 0.0f;
    for (int k = tid; k < H_SZ; k += 256) a += z2[(size_t)b * H_SZ + k] * W3[k];
    red[tid] = a; __syncthreads();
    for (int s = 128; s > 0; s >>= 1) { if (tid < s) red[tid] += red[tid + s]; __syncthreads(); }
    float zt = 1.0f / (1.0f + expf(-(red[0] + b3[0])));
    __syncthreads();

    float lv[8];
    float mx = -1e30f;
#pragma unroll
    for (int j = 0; j < 8; ++j) {
        int o = j * 256 + tid;
        lv[j] = (o < O_SZ) ? lo[(size_t)b * O_SZ + o] : -1e30f;
        mx = fmaxf(mx, lv[j]);
    }
    red[tid] = mx; __syncthreads();
    for (int s = 128; s > 0; s >>= 1) { if (tid < s) red[tid] = fmaxf(red[tid], red[tid + s]); __syncthreads(); }
    mx = red[0]; __syncthreads();

    float sm = 0.0f;
#pragma unroll
    for (int j = 0; j < 8; ++j) {
        lv[j] = expf(lv[j] - mx);
        sm += lv[j];
    }
    red[tid] = sm; __syncthreads();
    for (int s = 128; s > 0; s >>= 1) { if (tid < s) red[tid] += red[tid + s]; __syncthreads(); }
    float inv = 1.0f / red[0];

#pragma unroll
    for (int j = 0; j < 8; ++j) {
        int o = j * 256 + tid;
        if (o < O_SZ) pt[(size_t)b * 2104 + o] = logf(lv[j] * inv * zt + 1e-20f);
    }
    for (int l = tid; l < LC_SZ; l += 256)
        pt[(size_t)b * 2104 + O_SZ + l] = logf(attn_w[b * LC_SZ + l] * (1.0f - zt) + 1e-20f);
}

// ---------------------------------------------------------------------------
extern "C" void kernel_launch(void* const* d_in, const int* in_sizes, int n_in,
                              void* d_out, int out_size, void* d_ws, size_t ws_size,
                              hipStream_t stream)
{
    const int*   input   = (const int*)d_in[0];
    const int*   input_d = (const int*)d_in[1];
    const float* hidden  = (const float*)d_in[2];
    const float* annot   = (const float*)d_in[3];
    const float* ans     = (const float*)d_in[4];
    const float* emb_w   = (const float*)d_in[5];
    const float* emb_d_w = (const float*)d_in[6];
    const float* attn_W  = (const float*)d_in[7];
    const float* attn_b  = (const float*)d_in[8];
    const float* W_ih    = (const float*)d_in[9];
    const float* W_hh    = (const float*)d_in[10];
    const float* b_ih    = (const float*)d_in[11];
    const float* b_hh    = (const float*)d_in[12];
    const float* mlp_W   = (const float*)d_in[13];
    const float* mlp_b   = (const float*)d_in[14];
    const float* out_W   = (const float*)d_in[15];
    const float* out_b   = (const float*)d_in[16];
    const float* zt_W1   = (const float*)d_in[17];
    const float* zt_b1   = (const float*)d_in[18];
    const float* zt_W2   = (const float*)d_in[19];
    const float* zt_b2   = (const float*)d_in[20];
    const float* zt_W3   = (const float*)d_in[21];
    const float* zt_b3   = (const float*)d_in[22];

    char* p = (char*)d_ws;
    unsigned short* Wih_bf    = (unsigned short*)p; p += (size_t)1536 * GIK * 2;    //  4,079,616
    unsigned short* Whh_bf    = (unsigned short*)p; p += (size_t)1536 * 512 * 2;    //  1,572,864
    unsigned short* mlpW_bf   = (unsigned short*)p; p += (size_t)512 * XK * 2;      //  1,884,160
    unsigned short* outW_bf   = (unsigned short*)p; p += (size_t)2004 * 512 * 2;    //  2,052,096
    unsigned short* ztW1_bf   = (unsigned short*)p; p += (size_t)1024 * XK * 2;     //  3,768,320
    unsigned short* ztW2_bf   = (unsigned short*)p; p += (size_t)512 * 1024 * 2;    //  1,048,576
    unsigned short* Ahead     = (unsigned short*)p; p += (size_t)512 * HK * 2;      //  1,376,256
    unsigned short* xm_bf     = (unsigned short*)p; p += (size_t)512 * XK * 2;      //  1,884,160
    unsigned short* et_bf     = (unsigned short*)p; p += (size_t)512 * 512 * 2;     //    524,288
    unsigned short* z1_bf     = (unsigned short*)p; p += (size_t)512 * 1024 * 2;    //  1,048,576
    float* partial = (float*)p; p += (size_t)NSLICE * B_SZ * LC_SZ * 4;             // 17,817,600
    float* attn_w  = (float*)p; p += (size_t)B_SZ * LC_SZ * 4;                      //    204,800
    float* gi      = (float*)p; p += (size_t)512 * 1536 * 4;                        //  3,145,728
    float* gh      = (float*)p; p += (size_t)512 * 1536 * 4;                        //  3,145,728
    float* lo      = (float*)p; p += (size_t)512 * O_SZ * 4;                        //  4,104,192
    float* z2      = (float*)p; p += (size_t)512 * 512 * 4;                         // total ~49 MB

    float* out = (float*)d_out;

    cvt_weights<<<3517, 256, 0, stream>>>(W_ih, W_hh, mlp_W, out_W, zt_W1, zt_W2,
                                          Wih_bf, Whh_bf, mlpW_bf, outW_bf, ztW1_bf, ztW2_bf);
    build_head<<<2688, 256, 0, stream>>>(input, input_d, hidden, ans, emb_w, emb_d_w,
                                         Ahead, xm_bf);
    attn_gemm<<<dim3(8, NSLICE), 256, 0, stream>>>(annot, Ahead, attn_W, partial);
    attn_reduce_softmax<<<512, 128, 0, stream>>>(partial, attn_b, attn_w);
    attn_ct<<<dim3(B_SZ, 2), 256, 0, stream>>>(attn_w, annot, xm_bf);
    gigh_gemm<<<dim3(8, 48), 256, 0, stream>>>(xm_bf, Ahead, Wih_bf, Whh_bf, b_ih, b_hh, gi, gh);
    gru_kernel<<<1024, 256, 0, stream>>>(gi, gh, hidden, xm_bf, out);
    tail1_gemm<<<dim3(8, 24), 256, 0, stream>>>(xm_bf, mlpW_bf, ztW1_bf, mlp_b, zt_b1, et_bf, z1_bf);
    tail2_gemm<<<dim3(8, 40), 256, 0, stream>>>(et_bf, z1_bf, outW_bf, ztW2_bf, out_b, zt_b2, lo, z2);
    out_softmax<<<512, 256, 0, stream>>>(lo, attn_w, z2, zt_W3, zt_b3, out + 2 * B_SZ * H_SZ);
}

// Round 5
// 381.091 us; speedup vs baseline: 1.0490x; 1.0490x over previous
//
#include <hip/hip_runtime.h>
#include <cstddef>

typedef __attribute__((ext_vector_type(8))) short short8;
typedef __attribute__((ext_vector_type(4))) float f32x4;

#define B_SZ   512
#define H_SZ   512
#define E_SZ   300
#define LC_SZ  100
#define O_SZ   2004
#define HK     1344     // head K padded (real 1324 = 512 h0 + 300 emb + 512 ans)
#define NK     51200    // annot flat K (100*512)
#define AWK    52524    // attn_W row stride (f32 source)
#define XK     1840     // xm row stride (real 1836)
#define GIK    1328     // GRU-input K padded (real 1324)
#define NSLICE_A 80     // annot split-K slices (640 K each, 10 iters)
#define NSLICE_H 7      // head  split-K slices (192 K each, 3 iters)
#define NSLICE   87
#define ACHUNK 640
#define HCHUNK 192
#define CVT_BLKS 6083

__device__ __forceinline__ unsigned short f2bf(float f) {
    union { float f; unsigned u; } x; x.f = f;
    unsigned r = x.u + 0x7FFFu + ((x.u >> 16) & 1u);
    return (unsigned short)(r >> 16);
}
__device__ __forceinline__ unsigned pk2(float lo, float hi) {
    return (unsigned)f2bf(lo) | ((unsigned)f2bf(hi) << 16);
}

// ---------------------------------------------------------------------------
// Fused: weights f32 -> bf16 (blocks < CVT_BLKS) + build_head (rest).
// cvt segs: attnW-head, attnW-annot, W_ih, W_hh, mlp_W, out_W, zt_W1, zt_W2
// ---------------------------------------------------------------------------
__global__ __launch_bounds__(256) void cvt_build(
    const float* s_attn, const float* s_wih, const float* s_whh, const float* s_mlp,
    const float* s_out, const float* s_zt1, const float* s_zt2,
    unsigned short* d_wh, unsigned short* d_wn, unsigned short* d_wih,
    unsigned short* d_whh, unsigned short* d_mlp, unsigned short* d_out,
    unsigned short* d_zt1, unsigned short* d_zt2,
    const int* __restrict__ input, const int* __restrict__ input_d,
    const float* __restrict__ h0, const float* __restrict__ ans,
    const float* __restrict__ emb_w, const float* __restrict__ emb_d_w,
    unsigned short* __restrict__ Ahead, unsigned short* __restrict__ xm_bf)
{
    if (blockIdx.x >= CVT_BLKS) {
        // ---- build_head path ----
        int idx = (blockIdx.x - CVT_BLKS) * 256 + threadIdx.x;   // 512 * 1344
        if (idx >= B_SZ * HK) return;
        int b = idx / HK, c = idx - b * HK;
        unsigned short h = 0;
        if (c < 512) {
            h = f2bf(h0[(size_t)b * 512 + c]);
        } else if (c < 812) {
            int e = c - 512;
            int tok = input[b];
            float v;
            if (tok > 2003) {
                int di = tok - 2004;
                di = min(max(di, 0), LC_SZ - 1);
                int dt = input_d[b * LC_SZ + di];
                v = emb_d_w[(size_t)dt * E_SZ + e];
            } else {
                int t = min(max(tok, 0), 2103);
                v = emb_w[(size_t)t * E_SZ + e];
            }
            h = f2bf(v);
            xm_bf[(size_t)b * XK + 1536 + e] = h;
        } else if (c < 1324) {
            int a = c - 812;
            h = f2bf(ans[(size_t)b * 512 + a]);
            xm_bf[(size_t)b * XK + 1024 + a] = h;
        } else {
            if (c < 1328) xm_bf[(size_t)b * XK + 1836 + (c - 1324)] = 0;  // xm pad
        }
        Ahead[(size_t)b * HK + c] = h;
        return;
    }
    // ---- cvt path ----
    const int cum[8]   = {66, 2566, 3562, 3946, 4406, 4907, 5827, 6083};
    const int Ks[8]    = {1324, 51200, 1324, 512, 1836, 512, 1836, 1024};
    const int ldd[8]   = {1344, 51200, 1328, 512, 1840, 512, 1840, 1024};
    const int sstr[8]  = {52524, 52524, 1324, 512, 1836, 512, 1836, 1024};
    const int soff[8]  = {0, 1324, 0, 0, 0, 0, 0, 0};
    const int elems[8] = {134400, 5120000, 2039808, 786432, 942080, 1026048, 1884160, 524288};
    int blk = blockIdx.x;
    int seg = 0;
    while (seg < 7 && blk >= cum[seg]) seg++;
    int base = (seg == 0) ? 0 : cum[seg - 1];
    const float* src = seg < 2 ? s_attn : seg == 2 ? s_wih : seg == 3 ? s_whh :
                       seg == 4 ? s_mlp : seg == 5 ? s_out : seg == 6 ? s_zt1 : s_zt2;
    unsigned short* dst = seg==0?d_wh:seg==1?d_wn:seg==2?d_wih:seg==3?d_whh:
                          seg==4?d_mlp:seg==5?d_out:seg==6?d_zt1:d_zt2;
    int K = Ks[seg], L = ldd[seg], SS = sstr[seg], SO = soff[seg];
    int idx = (blk - base) * 2048 + threadIdx.x * 8;
    if (idx >= elems[seg]) return;
    int row = idx / L;
    int col = idx - row * L;
    unsigned short tmp[8];
    const float* sp = src + (size_t)row * SS + SO + col;
    if (col + 8 <= K) {
        float4 a = *(const float4*)sp;
        float4 b = *(const float4*)(sp + 4);
        tmp[0]=f2bf(a.x); tmp[1]=f2bf(a.y); tmp[2]=f2bf(a.z); tmp[3]=f2bf(a.w);
        tmp[4]=f2bf(b.x); tmp[5]=f2bf(b.y); tmp[6]=f2bf(b.z); tmp[7]=f2bf(b.w);
    } else {
        for (int j = 0; j < 8; ++j) {
            int c = col + j;
            tmp[j] = (c < K) ? f2bf(src[(size_t)row * SS + SO + c]) : (unsigned short)0;
        }
    }
    *(int4*)(dst + (size_t)row * L + col) = *(int4*)tmp;
}

// ---------------------------------------------------------------------------
// MFMA micro-step for 64x128 tile: 4 waves as 2(m) x 2(n), wave = 32x64
// ---------------------------------------------------------------------------
__device__ __forceinline__ void mfma_step128(
    unsigned short (*As)[72], unsigned short (*Bs)[72],
    int wm, int wn, int lane, f32x4 acc[2][4])
{
#pragma unroll
    for (int kk = 0; kk < 2; ++kk) {
        short8 a0 = *(const short8*)&As[wm * 32 +      (lane & 15)][kk * 32 + (lane >> 4) * 8];
        short8 a1 = *(const short8*)&As[wm * 32 + 16 + (lane & 15)][kk * 32 + (lane >> 4) * 8];
#pragma unroll
        for (int tt = 0; tt < 4; ++tt) {
            short8 bb = *(const short8*)&Bs[wn * 64 + tt * 16 + (lane & 15)][kk * 32 + (lane >> 4) * 8];
            acc[0][tt] = __builtin_amdgcn_mfma_f32_16x16x32_bf16(a0, bb, acc[0][tt], 0, 0, 0);
            acc[1][tt] = __builtin_amdgcn_mfma_f32_16x16x32_bf16(a1, bb, acc[1][tt], 0, 0, 0);
        }
    }
}

// ---------------------------------------------------------------------------
// Attention GEMM, split-K, single N pass (BN=128 covers N=100).
// bf16 W (precomputed), register-prefetch pipeline, XCD-clustered swizzle:
// each XCD gets ~11 consecutive z-slices with all 8 bm-blocks -> W slice
// fetched once per XCD instead of 8x.
// z < 80: annot slices (A f32 -> bf16 inline). z >= 80: head slices.
// ---------------------------------------------------------------------------
__global__ __launch_bounds__(256) void attn_gemm(
    const float* __restrict__ annot, const unsigned short* __restrict__ Ahead,
    const unsigned short* __restrict__ Wn, const unsigned short* __restrict__ Wh,
    float* __restrict__ partial)
{
    __shared__ unsigned short As[64][72];
    __shared__ unsigned short Bs[128][72];
    const int bid = blockIdx.x;                 // 0..695
    const int work = (bid & 7) * 87 + (bid >> 3);
    const int z  = work >> 3;                   // 0..86
    const int bm = (work & 7) * 64;
    const int t = threadIdx.x;
    const int lane = t & 63, w = t >> 6;
    const int wm = w >> 1, wn = w & 1;
    const int srow = t >> 2, scol = (t & 3) * 16;   // A staging: 4 thr/row, 16 cols
    const int brow = t >> 1, bcol = (t & 1) * 32;   // B staging: 2 thr/row, 32 cols
    const bool bv = (brow < LC_SZ);
    f32x4 acc[2][4] = {};
    const int4 zi4 = {0, 0, 0, 0};
    int4 rb[4] = {zi4, zi4, zi4, zi4};

    if (z < NSLICE_A) {
        const int kb = z * ACHUNK;
        float4 fa[4];
        // prefetch it=0
        {
            const float* ap = annot + (size_t)(bm + srow) * NK + kb + scol;
            fa[0] = ((const float4*)ap)[0]; fa[1] = ((const float4*)ap)[1];
            fa[2] = ((const float4*)ap)[2]; fa[3] = ((const float4*)ap)[3];
            if (bv) {
                const unsigned short* wp = Wn + (size_t)brow * NK + kb + bcol;
#pragma unroll
                for (int j = 0; j < 4; ++j) rb[j] = ((const int4*)wp)[j];
            }
        }
        for (int it = 0; it < 10; ++it) {
            int4 va0 = { (int)pk2(fa[0].x, fa[0].y), (int)pk2(fa[0].z, fa[0].w),
                         (int)pk2(fa[1].x, fa[1].y), (int)pk2(fa[1].z, fa[1].w) };
            int4 va1 = { (int)pk2(fa[2].x, fa[2].y), (int)pk2(fa[2].z, fa[2].w),
                         (int)pk2(fa[3].x, fa[3].y), (int)pk2(fa[3].z, fa[3].w) };
            *(int4*)&As[srow][scol]     = va0;
            *(int4*)&As[srow][scol + 8] = va1;
            *(int4*)&Bs[brow][bcol]      = rb[0];
            *(int4*)&Bs[brow][bcol + 8]  = rb[1];
            *(int4*)&Bs[brow][bcol + 16] = rb[2];
            *(int4*)&Bs[brow][bcol + 24] = rb[3];
            __syncthreads();
            if (it + 1 < 10) {
                int k0 = kb + (it + 1) * 64;
                const float* ap = annot + (size_t)(bm + srow) * NK + k0 + scol;
                fa[0] = ((const float4*)ap)[0]; fa[1] = ((const float4*)ap)[1];
                fa[2] = ((const float4*)ap)[2]; fa[3] = ((const float4*)ap)[3];
                if (bv) {
                    const unsigned short* wp = Wn + (size_t)brow * NK + k0 + bcol;
#pragma unroll
                    for (int j = 0; j < 4; ++j) rb[j] = ((const int4*)wp)[j];
                }
            }
            mfma_step128(As, Bs, wm, wn, lane, acc);
            __syncthreads();
        }
    } else {
        const int kb = (z - NSLICE_A) * HCHUNK;
        int4 ra0, ra1;
        // prefetch it=0  (Wh is padded to HK with zeros -> no edge handling)
        {
            const unsigned short* ap = Ahead + (size_t)(bm + srow) * HK + kb + scol;
            ra0 = ((const int4*)ap)[0]; ra1 = ((const int4*)ap)[1];
            if (bv) {
                const unsigned short* wp = Wh + (size_t)brow * HK + kb + bcol;
#pragma unroll
                for (int j = 0; j < 4; ++j) rb[j] = ((const int4*)wp)[j];
            }
        }
        for (int it = 0; it < 3; ++it) {
            *(int4*)&As[srow][scol]     = ra0;
            *(int4*)&As[srow][scol + 8] = ra1;
            *(int4*)&Bs[brow][bcol]      = rb[0];
            *(int4*)&Bs[brow][bcol + 8]  = rb[1];
            *(int4*)&Bs[brow][bcol + 16] = rb[2];
            *(int4*)&Bs[brow][bcol + 24] = rb[3];
            __syncthreads();
            if (it + 1 < 3) {
                int k0 = kb + (it + 1) * 64;
                const unsigned short* ap = Ahead + (size_t)(bm + srow) * HK + k0 + scol;
                ra0 = ((const int4*)ap)[0]; ra1 = ((const int4*)ap)[1];
                if (bv) {
                    const unsigned short* wp = Wh + (size_t)brow * HK + k0 + bcol;
#pragma unroll
                    for (int j = 0; j < 4; ++j) rb[j] = ((const int4*)wp)[j];
                }
            }
            mfma_step128(As, Bs, wm, wn, lane, acc);
            __syncthreads();
        }
    }
#pragma unroll
    for (int tt = 0; tt < 4; ++tt) {
        int n = wn * 64 + tt * 16 + (lane & 15);
        if (n >= LC_SZ) continue;
#pragma unroll
        for (int s = 0; s < 2; ++s) {
#pragma unroll
            for (int r = 0; r < 4; ++r) {
                int m = bm + wm * 32 + s * 16 + (lane >> 4) * 4 + r;
                partial[((size_t)z * B_SZ + m) * LC_SZ + n] = acc[s][tt][r];
            }
        }
    }
}

// ---------------------------------------------------------------------------
// Reduce partials (4 independent accumulators) + tanh + softmax(100)
// ---------------------------------------------------------------------------
__global__ __launch_bounds__(128) void attn_reduce_softmax(
    const float* __restrict__ partial, const float* __restrict__ attn_b,
    float* __restrict__ attn_w_out)
{
    int b = blockIdx.x, tid = threadIdx.x;
    __shared__ float red[128];

    float v = -1e30f;
    float e = 0.0f;
    if (tid < LC_SZ) {
        float s0 = 0.0f, s1 = 0.0f, s2 = 0.0f, s3 = 0.0f;
        const float* pp = partial + (size_t)b * LC_SZ + tid;
        int sp = 0;
        for (; sp + 4 <= NSLICE; sp += 4) {
            s0 += pp[(size_t)(sp    ) * B_SZ * LC_SZ];
            s1 += pp[(size_t)(sp + 1) * B_SZ * LC_SZ];
            s2 += pp[(size_t)(sp + 2) * B_SZ * LC_SZ];
            s3 += pp[(size_t)(sp + 3) * B_SZ * LC_SZ];
        }
        for (; sp < NSLICE; ++sp) s0 += pp[(size_t)sp * B_SZ * LC_SZ];
        v = tanhf(attn_b[tid] + s0 + s1 + s2 + s3);
    }
    red[tid] = v; __syncthreads();
    for (int s = 64; s > 0; s >>= 1) { if (tid < s) red[tid] = fmaxf(red[tid], red[tid + s]); __syncthreads(); }
    float mx = red[0]; __syncthreads();

    if (tid < LC_SZ) e = expf(v - mx);
    red[tid] = e; __syncthreads();
    for (int s = 64; s > 0; s >>= 1) { if (tid < s) red[tid] += red[tid + s]; __syncthreads(); }
    float denom = red[0];

    if (tid < LC_SZ) attn_w_out[b * LC_SZ + tid] = e / denom;
}

// ---------------------------------------------------------------------------
// c_t[b][h] = sum_l w[b][l] * annot[b][l][h]  — grid (b, h-half), high TLP
// ---------------------------------------------------------------------------
__global__ __launch_bounds__(256) void attn_ct(
    const float* __restrict__ attn_w, const float* __restrict__ annot,
    unsigned short* __restrict__ xm_bf)
{
    int b = blockIdx.x;
    int h = blockIdx.y * 256 + threadIdx.x;
    __shared__ float sw[LC_SZ];
    if (threadIdx.x < LC_SZ) sw[threadIdx.x] = attn_w[b * LC_SZ + threadIdx.x];
    __syncthreads();

    const float* ap = annot + (size_t)b * NK + h;
    float a0 = 0.0f, a1 = 0.0f, a2 = 0.0f, a3 = 0.0f;
#pragma unroll
    for (int l = 0; l < LC_SZ; l += 4) {
        a0 += sw[l    ] * ap[(l    ) * 512];
        a1 += sw[l + 1] * ap[(l + 1) * 512];
        a2 += sw[l + 2] * ap[(l + 2) * 512];
        a3 += sw[l + 3] * ap[(l + 3) * 512];
    }
    xm_bf[(size_t)b * XK + 512 + h] = f2bf((a0 + a1) + (a2 + a3));
}

// ---------------------------------------------------------------------------
// Shared 64x64 GEMM core (2x2 waves of 32x32), register-prefetch pipeline
// ---------------------------------------------------------------------------
__device__ __forceinline__ void gemm64_core(
    unsigned short (*As)[72], unsigned short (*Bs)[72],
    const unsigned short* Ablk, long lda,
    const unsigned short* Wblk, long ldw, int nrows,
    int Kpad, f32x4 acc[2][2])
{
    const int t = threadIdx.x;
    const int lane = t & 63, w = t >> 6;
    const int wm = w >> 1, wn = w & 1;
    const int srow = t >> 2, scol = (t & 3) * 16;
    const bool brv = (srow < nrows);
    int4 ra[2], rb[2];
#pragma unroll
    for (int i = 0; i < 2; ++i) {
        int gk = scol + i * 8;
        int4 v = {0, 0, 0, 0};
        if (gk < Kpad) v = *(const int4*)(Ablk + (size_t)srow * lda + gk);
        ra[i] = v;
        int4 u = {0, 0, 0, 0};
        if (gk < Kpad && brv) u = *(const int4*)(Wblk + (size_t)srow * ldw + gk);
        rb[i] = u;
    }
    for (int k0 = 0; k0 < Kpad; k0 += 64) {
        *(int4*)&As[srow][scol]     = ra[0];
        *(int4*)&As[srow][scol + 8] = ra[1];
        *(int4*)&Bs[srow][scol]     = rb[0];
        *(int4*)&Bs[srow][scol + 8] = rb[1];
        __syncthreads();
        if (k0 + 64 < Kpad) {
#pragma unroll
            for (int i = 0; i < 2; ++i) {
                int gk = k0 + 64 + scol + i * 8;
                int4 v = {0, 0, 0, 0};
                if (gk < Kpad) v = *(const int4*)(Ablk + (size_t)srow * lda + gk);
                ra[i] = v;
                int4 u = {0, 0, 0, 0};
                if (gk < Kpad && brv) u = *(const int4*)(Wblk + (size_t)srow * ldw + gk);
                rb[i] = u;
            }
        }
#pragma unroll
        for (int kk = 0; kk < 2; ++kk) {
            short8 a0 = *(const short8*)&As[wm * 32 +      (lane & 15)][kk * 32 + (lane >> 4) * 8];
            short8 a1 = *(const short8*)&As[wm * 32 + 16 + (lane & 15)][kk * 32 + (lane >> 4) * 8];
            short8 b0 = *(const short8*)&Bs[wn * 32 +      (lane & 15)][kk * 32 + (lane >> 4) * 8];
            short8 b1 = *(const short8*)&Bs[wn * 32 + 16 + (lane & 15)][kk * 32 + (lane >> 4) * 8];
            acc[0][0] = __builtin_amdgcn_mfma_f32_16x16x32_bf16(a0, b0, acc[0][0], 0, 0, 0);
            acc[0][1] = __builtin_amdgcn_mfma_f32_16x16x32_bf16(a0, b1, acc[0][1], 0, 0, 0);
            acc[1][0] = __builtin_amdgcn_mfma_f32_16x16x32_bf16(a1, b0, acc[1][0], 0, 0, 0);
            acc[1][1] = __builtin_amdgcn_mfma_f32_16x16x32_bf16(a1, b1, acc[1][1], 0, 0, 0);
        }
        __syncthreads();
    }
}

// ---------------------------------------------------------------------------
// gi = [c_t|ans|emb] @ W_ih^T + b_ih  (bn<24) ; gh = h0 @ W_hh^T + b_hh
// ---------------------------------------------------------------------------
__global__ __launch_bounds__(256) void gigh_gemm(
    const unsigned short* __restrict__ xm, const unsigned short* __restrict__ Ahead,
    const unsigned short* __restrict__ Wih, const unsigned short* __restrict__ Whh,
    const float* __restrict__ bih, const float* __restrict__ bhh,
    float* __restrict__ gi, float* __restrict__ gh)
{
    __shared__ unsigned short As[64][72];
    __shared__ unsigned short Bs[64][72];
    const int t = threadIdx.x;
    const int lane = t & 63, w = t >> 6;
    const int wm = w >> 1, wn = w & 1;
    const int bm = blockIdx.x * 64;
    const unsigned short* Ablk; long lda; const unsigned short* Wblk; long ldw;
    const float* bias; float* C; int Kpad, bn;
    if (blockIdx.y < 24) {
        bn = blockIdx.y * 64;
        Ablk = xm + (size_t)bm * XK + 512; lda = XK;
        Wblk = Wih + (size_t)bn * GIK;     ldw = GIK;
        bias = bih; C = gi; Kpad = GIK;
    } else {
        bn = (blockIdx.y - 24) * 64;
        Ablk = Ahead + (size_t)bm * HK;    lda = HK;
        Wblk = Whh + (size_t)bn * 512;     ldw = 512;
        bias = bhh; C = gh; Kpad = 512;
    }
    f32x4 acc[2][2] = {};
    gemm64_core(As, Bs, Ablk, lda, Wblk, ldw, 64, Kpad, acc);
#pragma unroll
    for (int tt = 0; tt < 2; ++tt) {
        int n = bn + wn * 32 + tt * 16 + (lane & 15);
        float bv = bias[n];
#pragma unroll
        for (int s = 0; s < 2; ++s)
#pragma unroll
            for (int r = 0; r < 4; ++r) {
                int m = bm + wm * 32 + s * 16 + (lane >> 4) * 4 + r;
                C[(size_t)m * 1536 + n] = acc[s][tt][r] + bv;
            }
    }
}

// ---------------------------------------------------------------------------
// GRU elementwise; h_new -> out slots 0/1 (f32) and xm_bf[b][0:512] (bf16)
// ---------------------------------------------------------------------------
__global__ __launch_bounds__(256) void gru_kernel(
    const float* __restrict__ gi, const float* __restrict__ gh,
    const float* __restrict__ h0, unsigned short* __restrict__ xm_bf,
    float* __restrict__ out01)
{
    int idx = blockIdx.x * 256 + threadIdx.x;   // B*H
    int b = idx >> 9, h = idx & 511;
    float ir  = gi[(size_t)b * 1536 + h];
    float iz  = gi[(size_t)b * 1536 + 512 + h];
    float inn = gi[(size_t)b * 1536 + 1024 + h];
    float hr  = gh[(size_t)b * 1536 + h];
    float hz  = gh[(size_t)b * 1536 + 512 + h];
    float hn  = gh[(size_t)b * 1536 + 1024 + h];
    float r = 1.0f / (1.0f + expf(-(ir + hr)));
    float z = 1.0f / (1.0f + expf(-(iz + hz)));
    float n = tanhf(inn + r * hn);
    float hp = h0[idx];
    float hv = (1.0f - z) * n + z * hp;
    xm_bf[(size_t)b * XK + h] = f2bf(hv);
    out01[idx] = hv;
    out01[B_SZ * H_SZ + idx] = hv;
}

// ---------------------------------------------------------------------------
// tail1: N=1536 fused — e_t = xm@mlp_W^T (bf16 out), z1 = tanh(xm@zt_W1^T)
// ---------------------------------------------------------------------------
__global__ __launch_bounds__(256) void tail1_gemm(
    const unsigned short* __restrict__ xm,
    const unsigned short* __restrict__ mlpW, const unsigned short* __restrict__ ztW1,
    const float* __restrict__ mlpb, const float* __restrict__ ztb1,
    unsigned short* __restrict__ et, unsigned short* __restrict__ z1)
{
    __shared__ unsigned short As[64][72];
    __shared__ unsigned short Bs[64][72];
    const int t = threadIdx.x;
    const int lane = t & 63, w = t >> 6;
    const int wm = w >> 1, wn = w & 1;
    const int bm = blockIdx.x * 64;
    const int mlp = blockIdx.y < 8;
    const int bn = mlp ? blockIdx.y * 64 : (blockIdx.y - 8) * 64;
    const unsigned short* Wblk = (mlp ? mlpW : ztW1) + (size_t)bn * XK;
    f32x4 acc[2][2] = {};
    gemm64_core(As, Bs, xm + (size_t)bm * XK, XK, Wblk, XK, 64, XK, acc);
#pragma unroll
    for (int tt = 0; tt < 2; ++tt) {
        int n = bn + wn * 32 + tt * 16 + (lane & 15);
        float bv = mlp ? mlpb[n] : ztb1[n];
#pragma unroll
        for (int s = 0; s < 2; ++s)
#pragma unroll
            for (int r = 0; r < 4; ++r) {
                int m = bm + wm * 32 + s * 16 + (lane >> 4) * 4 + r;
                float v = acc[s][tt][r] + bv;
                if (mlp) et[(size_t)m * 512 + n] = f2bf(v);
                else     z1[(size_t)m * 1024 + n] = f2bf(tanhf(v));
            }
    }
}

// ---------------------------------------------------------------------------
// tail2: fused — lo = e_t@out_W^T (bn<32), z2 = tanh(z1@zt_W2^T)
// ---------------------------------------------------------------------------
__global__ __launch_bounds__(256) void tail2_gemm(
    const unsigned short* __restrict__ et, const unsigned short* __restrict__ z1,
    const unsigned short* __restrict__ outW, const unsigned short* __restrict__ ztW2,
    const float* __restrict__ outb, const float* __restrict__ ztb2,
    float* __restrict__ lo, float* __restrict__ z2)
{
    __shared__ unsigned short As[64][72];
    __shared__ unsigned short Bs[64][72];
    const int t = threadIdx.x;
    const int lane = t & 63, w = t >> 6;
    const int wm = w >> 1, wn = w & 1;
    const int bm = blockIdx.x * 64;
    const int outp = blockIdx.y < 32;
    const int bn = outp ? blockIdx.y * 64 : (blockIdx.y - 32) * 64;
    const unsigned short* Ablk; long lda; const unsigned short* Wblk; long ldw;
    int Kpad, nrows;
    if (outp) {
        Ablk = et + (size_t)bm * 512; lda = 512;
        Wblk = outW + (size_t)bn * 512; ldw = 512;
        Kpad = 512; nrows = min(64, O_SZ - bn);
    } else {
        Ablk = z1 + (size_t)bm * 1024; lda = 1024;
        Wblk = ztW2 + (size_t)bn * 1024; ldw = 1024;
        Kpad = 1024; nrows = 64;
    }
    f32x4 acc[2][2] = {};
    gemm64_core(As, Bs, Ablk, lda, Wblk, ldw, nrows, Kpad, acc);
#pragma unroll
    for (int tt = 0; tt < 2; ++tt) {
        int n = bn + wn * 32 + tt * 16 + (lane & 15);
        if (outp && n >= O_SZ) continue;
        float bv = outp ? outb[n] : ztb2[n];
#pragma unroll
        for (int s = 0; s < 2; ++s)
#pragma unroll
            for (int r = 0; r < 4; ++r) {
                int m = bm + wm * 32 + s * 16 + (lane >> 4) * 4 + r;
                float v = acc[s][tt][r] + bv;
                if (outp) lo[(size_t)m * O_SZ + n] = v;
                else      z2[(size_t)m * 512 + n] = tanhf(v);
            }
    }
}

// ---------------------------------------------------------------------------
// Fused z_t dot + single-pass softmax over lo (row resident in registers)
// ---------------------------------------------------------------------------
__global__ __launch_bounds__(256) void out_softmax(
    const float* __restrict__ lo, const float* __restrict__ attn_w,
    const float* __restrict__ z2, const float* __restrict__ W3,
    const float* __restrict__ b3, float* __restrict__ pt)
{
    int b = blockIdx.x, tid = threadIdx.x;
    __shared__ float red[256];

    // z_t = sigmoid(z2[b] . W3 + b3)
    float a = 0.0f;
    for (int k = tid; k < H_SZ; k += 256) a += z2[(size_t)b * H_SZ + k] * W3[k];
    red[tid] = a; __syncthreads();
    for (int s = 128; s > 0; s >>= 1) { if (tid < s) red[tid] += red[tid + s]; __syncthreads(); }
    float zt = 1.0f / (1.0f + expf(-(red[0] + b3[0])));
    __syncthreads();

    float lv[8];
    float mx = -1e30f;
#pragma unroll
    for (int j = 0; j < 8; ++j) {
        int o = j * 256 + tid;
        lv[j] = (o < O_SZ) ? lo[(size_t)b * O_SZ + o] : -1e30f;
        mx = fmaxf(mx, lv[j]);
    }
    red[tid] = mx; __syncthreads();
    for (int s = 128; s > 0; s >>= 1) { if (tid < s) red[tid] = fmaxf(red[tid], red[tid + s]); __syncthreads(); }
    mx = red[0]; __syncthreads();

    float sm = 0.0f;
#pragma unroll
    for (int j = 0; j < 8; ++j) {
        lv[j] = expf(lv[j] - mx);
        sm += lv[j];
    }
    red[tid] = sm; __syncthreads();
    for (int s = 128; s > 0; s >>= 1) { if (tid < s) red[tid] += red[tid + s]; __syncthreads(); }
    float inv = 1.0f / red[0];

#pragma unroll
    for (int j = 0; j < 8; ++j) {
        int o = j * 256 + tid;
        if (o < O_SZ) pt[(size_t)b * 2104 + o] = logf(lv[j] * inv * zt + 1e-20f);
    }
    for (int l = tid; l < LC_SZ; l += 256)
        pt[(size_t)b * 2104 + O_SZ + l] = logf(attn_w[b * LC_SZ + l] * (1.0f - zt) + 1e-20f);
}

// ---------------------------------------------------------------------------
extern "C" void kernel_launch(void* const* d_in, const int* in_sizes, int n_in,
                              void* d_out, int out_size, void* d_ws, size_t ws_size,
                              hipStream_t stream)
{
    const int*   input   = (const int*)d_in[0];
    const int*   input_d = (const int*)d_in[1];
    const float* hidden  = (const float*)d_in[2];
    const float* annot   = (const float*)d_in[3];
    const float* ans     = (const float*)d_in[4];
    const float* emb_w   = (const float*)d_in[5];
    const float* emb_d_w = (const float*)d_in[6];
    const float* attn_W  = (const float*)d_in[7];
    const float* attn_b  = (const float*)d_in[8];
    const float* W_ih    = (const float*)d_in[9];
    const float* W_hh    = (const float*)d_in[10];
    const float* b_ih    = (const float*)d_in[11];
    const float* b_hh    = (const float*)d_in[12];
    const float* mlp_W   = (const float*)d_in[13];
    const float* mlp_b   = (const float*)d_in[14];
    const float* out_W   = (const float*)d_in[15];
    const float* out_b   = (const float*)d_in[16];
    const float* zt_W1   = (const float*)d_in[17];
    const float* zt_b1   = (const float*)d_in[18];
    const float* zt_W2   = (const float*)d_in[19];
    const float* zt_b2   = (const float*)d_in[20];
    const float* zt_W3   = (const float*)d_in[21];
    const float* zt_b3   = (const float*)d_in[22];

    char* p = (char*)d_ws;
    unsigned short* attnWh_bf = (unsigned short*)p; p += (size_t)100 * HK * 2;      //    268,800
    unsigned short* attnWn_bf = (unsigned short*)p; p += (size_t)100 * NK * 2;      // 10,240,000
    unsigned short* Wih_bf    = (unsigned short*)p; p += (size_t)1536 * GIK * 2;    //  4,079,616
    unsigned short* Whh_bf    = (unsigned short*)p; p += (size_t)1536 * 512 * 2;    //  1,572,864
    unsigned short* mlpW_bf   = (unsigned short*)p; p += (size_t)512 * XK * 2;      //  1,884,160
    unsigned short* outW_bf   = (unsigned short*)p; p += (size_t)2004 * 512 * 2;    //  2,052,096
    unsigned short* ztW1_bf   = (unsigned short*)p; p += (size_t)1024 * XK * 2;     //  3,768,320
    unsigned short* ztW2_bf   = (unsigned short*)p; p += (size_t)512 * 1024 * 2;    //  1,048,576
    unsigned short* Ahead     = (unsigned short*)p; p += (size_t)512 * HK * 2;      //  1,376,256
    unsigned short* xm_bf     = (unsigned short*)p; p += (size_t)512 * XK * 2;      //  1,884,160
    unsigned short* et_bf     = (unsigned short*)p; p += (size_t)512 * 512 * 2;     //    524,288
    unsigned short* z1_bf     = (unsigned short*)p; p += (size_t)512 * 1024 * 2;    //  1,048,576
    float* partial = (float*)p; p += (size_t)NSLICE * B_SZ * LC_SZ * 4;             // 17,817,600
    float* attn_w  = (float*)p; p += (size_t)B_SZ * LC_SZ * 4;                      //    204,800
    float* gi      = (float*)p; p += (size_t)512 * 1536 * 4;                        //  3,145,728
    float* gh      = (float*)p; p += (size_t)512 * 1536 * 4;                        //  3,145,728
    float* lo      = (float*)p; p += (size_t)512 * O_SZ * 4;                        //  4,104,192
    float* z2      = (float*)p; p += (size_t)512 * 512 * 4;                         // total ~59 MB

    float* out = (float*)d_out;

    cvt_build<<<CVT_BLKS + 2688, 256, 0, stream>>>(
        attn_W, W_ih, W_hh, mlp_W, out_W, zt_W1, zt_W2,
        attnWh_bf, attnWn_bf, Wih_bf, Whh_bf, mlpW_bf, outW_bf, ztW1_bf, ztW2_bf,
        input, input_d, hidden, ans, emb_w, emb_d_w, Ahead, xm_bf);
    attn_gemm<<<696, 256, 0, stream>>>(annot, Ahead, attnWn_bf, attnWh_bf, partial);
    attn_reduce_softmax<<<512, 128, 0, stream>>>(partial, attn_b, attn_w);
    attn_ct<<<dim3(B_SZ, 2), 256, 0, stream>>>(attn_w, annot, xm_bf);
    gigh_gemm<<<dim3(8, 48), 256, 0, stream>>>(xm_bf, Ahead, Wih_bf, Whh_bf, b_ih, b_hh, gi, gh);
    gru_kernel<<<1024, 256, 0, stream>>>(gi, gh, hidden, xm_bf, out);
    tail1_gemm<<<dim3(8, 24), 256, 0, stream>>>(xm_bf, mlpW_bf, ztW1_bf, mlp_b, zt_b1, et_bf, z1_bf);
    tail2_gemm<<<dim3(8, 40), 256, 0, stream>>>(et_bf, z1_bf, outW_bf, ztW2_bf, out_b, zt_b2, lo, z2);
    out_softmax<<<512, 256, 0, stream>>>(lo, attn_w, z2, zt_W3, zt_b3, out + 2 * B_SZ * H_SZ);
}

// Round 6
// 356.208 us; speedup vs baseline: 1.1223x; 1.0699x over previous
//
#include <hip/hip_runtime.h>
#include <cstddef>

typedef __attribute__((ext_vector_type(8))) short short8;
typedef __attribute__((ext_vector_type(4))) float f32x4;

#define B_SZ   512
#define H_SZ   512
#define E_SZ   300
#define LC_SZ  100
#define O_SZ   2004
#define HK     1344     // head K padded (real 1324 = 512 h0 + 300 emb + 512 ans)
#define NK     51200    // annot flat K (100*512)
#define AWK    52524    // attn_W row stride (f32 source)
#define XK     1840     // xm row stride (real 1836)
#define GIK    1328     // GRU-input K padded (real 1324)
#define NSLICE_A 80     // annot split-K slices (640 K each, 10 iters)
#define NSLICE_H 7      // head  split-K slices (192 K each, 3 iters)
#define NSLICE   87
#define ACHUNK 640
#define HCHUNK 192
#define CVT_BLKS 6083

__device__ __forceinline__ unsigned short f2bf(float f) {
    union { float f; unsigned u; } x; x.f = f;
    unsigned r = x.u + 0x7FFFu + ((x.u >> 16) & 1u);
    return (unsigned short)(r >> 16);
}
__device__ __forceinline__ unsigned pk2(float lo, float hi) {
    return (unsigned)f2bf(lo) | ((unsigned)f2bf(hi) << 16);
}

// ---------------------------------------------------------------------------
// Fused: weights f32 -> bf16 (blocks < CVT_BLKS) + build_head (rest).
// cvt segs: attnW-head, attnW-annot, W_ih, W_hh, mlp_W, out_W, zt_W1, zt_W2
// ---------------------------------------------------------------------------
__global__ __launch_bounds__(256) void cvt_build(
    const float* s_attn, const float* s_wih, const float* s_whh, const float* s_mlp,
    const float* s_out, const float* s_zt1, const float* s_zt2,
    unsigned short* d_wh, unsigned short* d_wn, unsigned short* d_wih,
    unsigned short* d_whh, unsigned short* d_mlp, unsigned short* d_out,
    unsigned short* d_zt1, unsigned short* d_zt2,
    const int* __restrict__ input, const int* __restrict__ input_d,
    const float* __restrict__ h0, const float* __restrict__ ans,
    const float* __restrict__ emb_w, const float* __restrict__ emb_d_w,
    unsigned short* __restrict__ Ahead, unsigned short* __restrict__ xm_bf)
{
    if (blockIdx.x >= CVT_BLKS) {
        // ---- build_head path ----
        int idx = (blockIdx.x - CVT_BLKS) * 256 + threadIdx.x;   // 512 * 1344
        if (idx >= B_SZ * HK) return;
        int b = idx / HK, c = idx - b * HK;
        unsigned short h = 0;
        if (c < 512) {
            h = f2bf(h0[(size_t)b * 512 + c]);
        } else if (c < 812) {
            int e = c - 512;
            int tok = input[b];
            float v;
            if (tok > 2003) {
                int di = tok - 2004;
                di = min(max(di, 0), LC_SZ - 1);
                int dt = input_d[b * LC_SZ + di];
                v = emb_d_w[(size_t)dt * E_SZ + e];
            } else {
                int t = min(max(tok, 0), 2103);
                v = emb_w[(size_t)t * E_SZ + e];
            }
            h = f2bf(v);
            xm_bf[(size_t)b * XK + 1536 + e] = h;
        } else if (c < 1324) {
            int a = c - 812;
            h = f2bf(ans[(size_t)b * 512 + a]);
            xm_bf[(size_t)b * XK + 1024 + a] = h;
        } else {
            if (c < 1328) xm_bf[(size_t)b * XK + 1836 + (c - 1324)] = 0;  // xm pad
        }
        Ahead[(size_t)b * HK + c] = h;
        return;
    }
    // ---- cvt path ----
    const int cum[8]   = {66, 2566, 3562, 3946, 4406, 4907, 5827, 6083};
    const int Ks[8]    = {1324, 51200, 1324, 512, 1836, 512, 1836, 1024};
    const int ldd[8]   = {1344, 51200, 1328, 512, 1840, 512, 1840, 1024};
    const int sstr[8]  = {52524, 52524, 1324, 512, 1836, 512, 1836, 1024};
    const int soff[8]  = {0, 1324, 0, 0, 0, 0, 0, 0};
    const int elems[8] = {134400, 5120000, 2039808, 786432, 942080, 1026048, 1884160, 524288};
    int blk = blockIdx.x;
    int seg = 0;
    while (seg < 7 && blk >= cum[seg]) seg++;
    int base = (seg == 0) ? 0 : cum[seg - 1];
    const float* src = seg < 2 ? s_attn : seg == 2 ? s_wih : seg == 3 ? s_whh :
                       seg == 4 ? s_mlp : seg == 5 ? s_out : seg == 6 ? s_zt1 : s_zt2;
    unsigned short* dst = seg==0?d_wh:seg==1?d_wn:seg==2?d_wih:seg==3?d_whh:
                          seg==4?d_mlp:seg==5?d_out:seg==6?d_zt1:d_zt2;
    int K = Ks[seg], L = ldd[seg], SS = sstr[seg], SO = soff[seg];
    int idx = (blk - base) * 2048 + threadIdx.x * 8;
    if (idx >= elems[seg]) return;
    int row = idx / L;
    int col = idx - row * L;
    unsigned short tmp[8];
    const float* sp = src + (size_t)row * SS + SO + col;
    if (col + 8 <= K) {
        float4 a = *(const float4*)sp;
        float4 b = *(const float4*)(sp + 4);
        tmp[0]=f2bf(a.x); tmp[1]=f2bf(a.y); tmp[2]=f2bf(a.z); tmp[3]=f2bf(a.w);
        tmp[4]=f2bf(b.x); tmp[5]=f2bf(b.y); tmp[6]=f2bf(b.z); tmp[7]=f2bf(b.w);
    } else {
        for (int j = 0; j < 8; ++j) {
            int c = col + j;
            tmp[j] = (c < K) ? f2bf(src[(size_t)row * SS + SO + c]) : (unsigned short)0;
        }
    }
    *(int4*)(dst + (size_t)row * L + col) = *(int4*)tmp;
}

// ---------------------------------------------------------------------------
// Attention GEMM, split-K, single N pass (BN=128 covers N=100).
// 512 threads / 8 waves (2m x 4n, 32x32 per wave) -> half the per-thread
// register pressure of the 256-thr version (round-5 spill fix: VGPR live set
// ~50, no scratch). Register-prefetch pipeline + XCD-clustered swizzle.
// z < 80: annot slices (A f32 -> bf16 inline). z >= 80: head slices.
// ---------------------------------------------------------------------------
__global__ __launch_bounds__(512) void attn_gemm(
    const float* __restrict__ annot, const unsigned short* __restrict__ Ahead,
    const unsigned short* __restrict__ Wn, const unsigned short* __restrict__ Wh,
    float* __restrict__ partial)
{
    __shared__ unsigned short As[64][72];
    __shared__ unsigned short Bs[128][72];
    const int bid = blockIdx.x;                 // 0..695
    const int work = (bid & 7) * 87 + (bid >> 3);
    const int z  = work >> 3;                   // 0..86
    const int bm = (work & 7) * 64;
    const int t = threadIdx.x;
    const int lane = t & 63, w = t >> 6;
    const int wm = w >> 2, wn = w & 3;          // 2 x 4 waves, 32x32 each
    const int srow = t >> 3, scol = (t & 7) * 8;    // A staging: 8 thr/row, 8 cols
    const int brow = t >> 2, bcol = (t & 3) * 16;   // B staging: 4 thr/row, 16 cols
    const bool bv = (brow < LC_SZ);
    f32x4 acc[2][2] = {};
    const int4 zi4 = {0, 0, 0, 0};
    int4 rb0 = zi4, rb1 = zi4;

    if (z < NSLICE_A) {
        const int kb = z * ACHUNK;
        float4 fa0, fa1;
        // prefetch it=0
        {
            const float* ap = annot + (size_t)(bm + srow) * NK + kb + scol;
            fa0 = ((const float4*)ap)[0]; fa1 = ((const float4*)ap)[1];
            if (bv) {
                const unsigned short* wp = Wn + (size_t)brow * NK + kb + bcol;
                rb0 = ((const int4*)wp)[0]; rb1 = ((const int4*)wp)[1];
            }
        }
        for (int it = 0; it < 10; ++it) {
            int4 va = { (int)pk2(fa0.x, fa0.y), (int)pk2(fa0.z, fa0.w),
                        (int)pk2(fa1.x, fa1.y), (int)pk2(fa1.z, fa1.w) };
            *(int4*)&As[srow][scol]     = va;
            *(int4*)&Bs[brow][bcol]     = rb0;
            *(int4*)&Bs[brow][bcol + 8] = rb1;
            __syncthreads();
            if (it + 1 < 10) {
                int k0 = kb + (it + 1) * 64;
                const float* ap = annot + (size_t)(bm + srow) * NK + k0 + scol;
                fa0 = ((const float4*)ap)[0]; fa1 = ((const float4*)ap)[1];
                if (bv) {
                    const unsigned short* wp = Wn + (size_t)brow * NK + k0 + bcol;
                    rb0 = ((const int4*)wp)[0]; rb1 = ((const int4*)wp)[1];
                }
            }
#pragma unroll
            for (int kk = 0; kk < 2; ++kk) {
                short8 a0 = *(const short8*)&As[wm * 32 +      (lane & 15)][kk * 32 + (lane >> 4) * 8];
                short8 a1 = *(const short8*)&As[wm * 32 + 16 + (lane & 15)][kk * 32 + (lane >> 4) * 8];
                short8 b0 = *(const short8*)&Bs[wn * 32 +      (lane & 15)][kk * 32 + (lane >> 4) * 8];
                short8 b1 = *(const short8*)&Bs[wn * 32 + 16 + (lane & 15)][kk * 32 + (lane >> 4) * 8];
                acc[0][0] = __builtin_amdgcn_mfma_f32_16x16x32_bf16(a0, b0, acc[0][0], 0, 0, 0);
                acc[0][1] = __builtin_amdgcn_mfma_f32_16x16x32_bf16(a0, b1, acc[0][1], 0, 0, 0);
                acc[1][0] = __builtin_amdgcn_mfma_f32_16x16x32_bf16(a1, b0, acc[1][0], 0, 0, 0);
                acc[1][1] = __builtin_amdgcn_mfma_f32_16x16x32_bf16(a1, b1, acc[1][1], 0, 0, 0);
            }
            __syncthreads();
        }
    } else {
        const int kb = (z - NSLICE_A) * HCHUNK;
        int4 ra;
        // prefetch it=0  (Wh is padded to HK with zeros -> no edge handling)
        {
            const unsigned short* ap = Ahead + (size_t)(bm + srow) * HK + kb + scol;
            ra = ((const int4*)ap)[0];
            if (bv) {
                const unsigned short* wp = Wh + (size_t)brow * HK + kb + bcol;
                rb0 = ((const int4*)wp)[0]; rb1 = ((const int4*)wp)[1];
            }
        }
        for (int it = 0; it < 3; ++it) {
            *(int4*)&As[srow][scol]     = ra;
            *(int4*)&Bs[brow][bcol]     = rb0;
            *(int4*)&Bs[brow][bcol + 8] = rb1;
            __syncthreads();
            if (it + 1 < 3) {
                int k0 = kb + (it + 1) * 64;
                const unsigned short* ap = Ahead + (size_t)(bm + srow) * HK + k0 + scol;
                ra = ((const int4*)ap)[0];
                if (bv) {
                    const unsigned short* wp = Wh + (size_t)brow * HK + k0 + bcol;
                    rb0 = ((const int4*)wp)[0]; rb1 = ((const int4*)wp)[1];
                }
            }
#pragma unroll
            for (int kk = 0; kk < 2; ++kk) {
                short8 a0 = *(const short8*)&As[wm * 32 +      (lane & 15)][kk * 32 + (lane >> 4) * 8];
                short8 a1 = *(const short8*)&As[wm * 32 + 16 + (lane & 15)][kk * 32 + (lane >> 4) * 8];
                short8 b0 = *(const short8*)&Bs[wn * 32 +      (lane & 15)][kk * 32 + (lane >> 4) * 8];
                short8 b1 = *(const short8*)&Bs[wn * 32 + 16 + (lane & 15)][kk * 32 + (lane >> 4) * 8];
                acc[0][0] = __builtin_amdgcn_mfma_f32_16x16x32_bf16(a0, b0, acc[0][0], 0, 0, 0);
                acc[0][1] = __builtin_amdgcn_mfma_f32_16x16x32_bf16(a0, b1, acc[0][1], 0, 0, 0);
                acc[1][0] = __builtin_amdgcn_mfma_f32_16x16x32_bf16(a1, b0, acc[1][0], 0, 0, 0);
                acc[1][1] = __builtin_amdgcn_mfma_f32_16x16x32_bf16(a1, b1, acc[1][1], 0, 0, 0);
            }
            __syncthreads();
        }
    }
#pragma unroll
    for (int tt = 0; tt < 2; ++tt) {
        int n = wn * 32 + tt * 16 + (lane & 15);
        if (n >= LC_SZ) continue;
#pragma unroll
        for (int s = 0; s < 2; ++s) {
#pragma unroll
            for (int r = 0; r < 4; ++r) {
                int m = bm + wm * 32 + s * 16 + (lane >> 4) * 4 + r;
                partial[((size_t)z * B_SZ + m) * LC_SZ + n] = acc[s][tt][r];
            }
        }
    }
}

// ---------------------------------------------------------------------------
// Reduce partials (4 independent accumulators) + tanh + softmax(100)
// ---------------------------------------------------------------------------
__global__ __launch_bounds__(128) void attn_reduce_softmax(
    const float* __restrict__ partial, const float* __restrict__ attn_b,
    float* __restrict__ attn_w_out)
{
    int b = blockIdx.x, tid = threadIdx.x;
    __shared__ float red[128];

    float v = -1e30f;
    float e = 0.0f;
    if (tid < LC_SZ) {
        float s0 = 0.0f, s1 = 0.0f, s2 = 0.0f, s3 = 0.0f;
        const float* pp = partial + (size_t)b * LC_SZ + tid;
        int sp = 0;
        for (; sp + 4 <= NSLICE; sp += 4) {
            s0 += pp[(size_t)(sp    ) * B_SZ * LC_SZ];
            s1 += pp[(size_t)(sp + 1) * B_SZ * LC_SZ];
            s2 += pp[(size_t)(sp + 2) * B_SZ * LC_SZ];
            s3 += pp[(size_t)(sp + 3) * B_SZ * LC_SZ];
        }
        for (; sp < NSLICE; ++sp) s0 += pp[(size_t)sp * B_SZ * LC_SZ];
        v = tanhf(attn_b[tid] + s0 + s1 + s2 + s3);
    }
    red[tid] = v; __syncthreads();
    for (int s = 64; s > 0; s >>= 1) { if (tid < s) red[tid] = fmaxf(red[tid], red[tid + s]); __syncthreads(); }
    float mx = red[0]; __syncthreads();

    if (tid < LC_SZ) e = expf(v - mx);
    red[tid] = e; __syncthreads();
    for (int s = 64; s > 0; s >>= 1) { if (tid < s) red[tid] += red[tid + s]; __syncthreads(); }
    float denom = red[0];

    if (tid < LC_SZ) attn_w_out[b * LC_SZ + tid] = e / denom;
}

// ---------------------------------------------------------------------------
// c_t[b][h] = sum_l w[b][l] * annot[b][l][h]  — grid (b, h-half), high TLP
// ---------------------------------------------------------------------------
__global__ __launch_bounds__(256) void attn_ct(
    const float* __restrict__ attn_w, const float* __restrict__ annot,
    unsigned short* __restrict__ xm_bf)
{
    int b = blockIdx.x;
    int h = blockIdx.y * 256 + threadIdx.x;
    __shared__ float sw[LC_SZ];
    if (threadIdx.x < LC_SZ) sw[threadIdx.x] = attn_w[b * LC_SZ + threadIdx.x];
    __syncthreads();

    const float* ap = annot + (size_t)b * NK + h;
    float a0 = 0.0f, a1 = 0.0f, a2 = 0.0f, a3 = 0.0f;
#pragma unroll
    for (int l = 0; l < LC_SZ; l += 4) {
        a0 += sw[l    ] * ap[(l    ) * 512];
        a1 += sw[l + 1] * ap[(l + 1) * 512];
        a2 += sw[l + 2] * ap[(l + 2) * 512];
        a3 += sw[l + 3] * ap[(l + 3) * 512];
    }
    xm_bf[(size_t)b * XK + 512 + h] = f2bf((a0 + a1) + (a2 + a3));
}

// ---------------------------------------------------------------------------
// Shared 64x64 GEMM core (2x2 waves of 32x32), register-prefetch pipeline
// ---------------------------------------------------------------------------
__device__ __forceinline__ void gemm64_core(
    unsigned short (*As)[72], unsigned short (*Bs)[72],
    const unsigned short* Ablk, long lda,
    const unsigned short* Wblk, long ldw, int nrows,
    int Kpad, f32x4 acc[2][2])
{
    const int t = threadIdx.x;
    const int lane = t & 63, w = t >> 6;
    const int wm = w >> 1, wn = w & 1;
    const int srow = t >> 2, scol = (t & 3) * 16;
    const bool brv = (srow < nrows);
    int4 ra[2], rb[2];
#pragma unroll
    for (int i = 0; i < 2; ++i) {
        int gk = scol + i * 8;
        int4 v = {0, 0, 0, 0};
        if (gk < Kpad) v = *(const int4*)(Ablk + (size_t)srow * lda + gk);
        ra[i] = v;
        int4 u = {0, 0, 0, 0};
        if (gk < Kpad && brv) u = *(const int4*)(Wblk + (size_t)srow * ldw + gk);
        rb[i] = u;
    }
    for (int k0 = 0; k0 < Kpad; k0 += 64) {
        *(int4*)&As[srow][scol]     = ra[0];
        *(int4*)&As[srow][scol + 8] = ra[1];
        *(int4*)&Bs[srow][scol]     = rb[0];
        *(int4*)&Bs[srow][scol + 8] = rb[1];
        __syncthreads();
        if (k0 + 64 < Kpad) {
#pragma unroll
            for (int i = 0; i < 2; ++i) {
                int gk = k0 + 64 + scol + i * 8;
                int4 v = {0, 0, 0, 0};
                if (gk < Kpad) v = *(const int4*)(Ablk + (size_t)srow * lda + gk);
                ra[i] = v;
                int4 u = {0, 0, 0, 0};
                if (gk < Kpad && brv) u = *(const int4*)(Wblk + (size_t)srow * ldw + gk);
                rb[i] = u;
            }
        }
#pragma unroll
        for (int kk = 0; kk < 2; ++kk) {
            short8 a0 = *(const short8*)&As[wm * 32 +      (lane & 15)][kk * 32 + (lane >> 4) * 8];
            short8 a1 = *(const short8*)&As[wm * 32 + 16 + (lane & 15)][kk * 32 + (lane >> 4) * 8];
            short8 b0 = *(const short8*)&Bs[wn * 32 +      (lane & 15)][kk * 32 + (lane >> 4) * 8];
            short8 b1 = *(const short8*)&Bs[wn * 32 + 16 + (lane & 15)][kk * 32 + (lane >> 4) * 8];
            acc[0][0] = __builtin_amdgcn_mfma_f32_16x16x32_bf16(a0, b0, acc[0][0], 0, 0, 0);
            acc[0][1] = __builtin_amdgcn_mfma_f32_16x16x32_bf16(a0, b1, acc[0][1], 0, 0, 0);
            acc[1][0] = __builtin_amdgcn_mfma_f32_16x16x32_bf16(a1, b0, acc[1][0], 0, 0, 0);
            acc[1][1] = __builtin_amdgcn_mfma_f32_16x16x32_bf16(a1, b1, acc[1][1], 0, 0, 0);
        }
        __syncthreads();
    }
}

// ---------------------------------------------------------------------------
// gi = [c_t|ans|emb] @ W_ih^T + b_ih  (bn<24) ; gh = h0 @ W_hh^T + b_hh
// ---------------------------------------------------------------------------
__global__ __launch_bounds__(256) void gigh_gemm(
    const unsigned short* __restrict__ xm, const unsigned short* __restrict__ Ahead,
    const unsigned short* __restrict__ Wih, const unsigned short* __restrict__ Whh,
    const float* __restrict__ bih, const float* __restrict__ bhh,
    float* __restrict__ gi, float* __restrict__ gh)
{
    __shared__ unsigned short As[64][72];
    __shared__ unsigned short Bs[64][72];
    const int t = threadIdx.x;
    const int lane = t & 63, w = t >> 6;
    const int wm = w >> 1, wn = w & 1;
    const int bm = blockIdx.x * 64;
    const unsigned short* Ablk; long lda; const unsigned short* Wblk; long ldw;
    const float* bias; float* C; int Kpad, bn;
    if (blockIdx.y < 24) {
        bn = blockIdx.y * 64;
        Ablk = xm + (size_t)bm * XK + 512; lda = XK;
        Wblk = Wih + (size_t)bn * GIK;     ldw = GIK;
        bias = bih; C = gi; Kpad = GIK;
    } else {
        bn = (blockIdx.y - 24) * 64;
        Ablk = Ahead + (size_t)bm * HK;    lda = HK;
        Wblk = Whh + (size_t)bn * 512;     ldw = 512;
        bias = bhh; C = gh; Kpad = 512;
    }
    f32x4 acc[2][2] = {};
    gemm64_core(As, Bs, Ablk, lda, Wblk, ldw, 64, Kpad, acc);
#pragma unroll
    for (int tt = 0; tt < 2; ++tt) {
        int n = bn + wn * 32 + tt * 16 + (lane & 15);
        float bv = bias[n];
#pragma unroll
        for (int s = 0; s < 2; ++s)
#pragma unroll
            for (int r = 0; r < 4; ++r) {
                int m = bm + wm * 32 + s * 16 + (lane >> 4) * 4 + r;
                C[(size_t)m * 1536 + n] = acc[s][tt][r] + bv;
            }
    }
}

// ---------------------------------------------------------------------------
// GRU elementwise; h_new -> out slots 0/1 (f32) and xm_bf[b][0:512] (bf16)
// ---------------------------------------------------------------------------
__global__ __launch_bounds__(256) void gru_kernel(
    const float* __restrict__ gi, const float* __restrict__ gh,
    const float* __restrict__ h0, unsigned short* __restrict__ xm_bf,
    float* __restrict__ out01)
{
    int idx = blockIdx.x * 256 + threadIdx.x;   // B*H
    int b = idx >> 9, h = idx & 511;
    float ir  = gi[(size_t)b * 1536 + h];
    float iz  = gi[(size_t)b * 1536 + 512 + h];
    float inn = gi[(size_t)b * 1536 + 1024 + h];
    float hr  = gh[(size_t)b * 1536 + h];
    float hz  = gh[(size_t)b * 1536 + 512 + h];
    float hn  = gh[(size_t)b * 1536 + 1024 + h];
    float r = 1.0f / (1.0f + expf(-(ir + hr)));
    float z = 1.0f / (1.0f + expf(-(iz + hz)));
    float n = tanhf(inn + r * hn);
    float hp = h0[idx];
    float hv = (1.0f - z) * n + z * hp;
    xm_bf[(size_t)b * XK + h] = f2bf(hv);
    out01[idx] = hv;
    out01[B_SZ * H_SZ + idx] = hv;
}

// ---------------------------------------------------------------------------
// tail1: N=1536 fused — e_t = xm@mlp_W^T (bf16 out), z1 = tanh(xm@zt_W1^T)
// ---------------------------------------------------------------------------
__global__ __launch_bounds__(256) void tail1_gemm(
    const unsigned short* __restrict__ xm,
    const unsigned short* __restrict__ mlpW, const unsigned short* __restrict__ ztW1,
    const float* __restrict__ mlpb, const float* __restrict__ ztb1,
    unsigned short* __restrict__ et, unsigned short* __restrict__ z1)
{
    __shared__ unsigned short As[64][72];
    __shared__ unsigned short Bs[64][72];
    const int t = threadIdx.x;
    const int lane = t & 63, w = t >> 6;
    const int wm = w >> 1, wn = w & 1;
    const int bm = blockIdx.x * 64;
    const int mlp = blockIdx.y < 8;
    const int bn = mlp ? blockIdx.y * 64 : (blockIdx.y - 8) * 64;
    const unsigned short* Wblk = (mlp ? mlpW : ztW1) + (size_t)bn * XK;
    f32x4 acc[2][2] = {};
    gemm64_core(As, Bs, xm + (size_t)bm * XK, XK, Wblk, XK, 64, XK, acc);
#pragma unroll
    for (int tt = 0; tt < 2; ++tt) {
        int n = bn + wn * 32 + tt * 16 + (lane & 15);
        float bv = mlp ? mlpb[n] : ztb1[n];
#pragma unroll
        for (int s = 0; s < 2; ++s)
#pragma unroll
            for (int r = 0; r < 4; ++r) {
                int m = bm + wm * 32 + s * 16 + (lane >> 4) * 4 + r;
                float v = acc[s][tt][r] + bv;
                if (mlp) et[(size_t)m * 512 + n] = f2bf(v);
                else     z1[(size_t)m * 1024 + n] = f2bf(tanhf(v));
            }
    }
}

// ---------------------------------------------------------------------------
// tail2: fused — lo = e_t@out_W^T (bn<32), z2 = tanh(z1@zt_W2^T)
// ---------------------------------------------------------------------------
__global__ __launch_bounds__(256) void tail2_gemm(
    const unsigned short* __restrict__ et, const unsigned short* __restrict__ z1,
    const unsigned short* __restrict__ outW, const unsigned short* __restrict__ ztW2,
    const float* __restrict__ outb, const float* __restrict__ ztb2,
    float* __restrict__ lo, float* __restrict__ z2)
{
    __shared__ unsigned short As[64][72];
    __shared__ unsigned short Bs[64][72];
    const int t = threadIdx.x;
    const int lane = t & 63, w = t >> 6;
    const int wm = w >> 1, wn = w & 1;
    const int bm = blockIdx.x * 64;
    const int outp = blockIdx.y < 32;
    const int bn = outp ? blockIdx.y * 64 : (blockIdx.y - 32) * 64;
    const unsigned short* Ablk; long lda; const unsigned short* Wblk; long ldw;
    int Kpad, nrows;
    if (outp) {
        Ablk = et + (size_t)bm * 512; lda = 512;
        Wblk = outW + (size_t)bn * 512; ldw = 512;
        Kpad = 512; nrows = min(64, O_SZ - bn);
    } else {
        Ablk = z1 + (size_t)bm * 1024; lda = 1024;
        Wblk = ztW2 + (size_t)bn * 1024; ldw = 1024;
        Kpad = 1024; nrows = 64;
    }
    f32x4 acc[2][2] = {};
    gemm64_core(As, Bs, Ablk, lda, Wblk, ldw, nrows, Kpad, acc);
#pragma unroll
    for (int tt = 0; tt < 2; ++tt) {
        int n = bn + wn * 32 + tt * 16 + (lane & 15);
        if (outp && n >= O_SZ) continue;
        float bv = outp ? outb[n] : ztb2[n];
#pragma unroll
        for (int s = 0; s < 2; ++s)
#pragma unroll
            for (int r = 0; r < 4; ++r) {
                int m = bm + wm * 32 + s * 16 + (lane >> 4) * 4 + r;
                float v = acc[s][tt][r] + bv;
                if (outp) lo[(size_t)m * O_SZ + n] = v;
                else      z2[(size_t)m * 512 + n] = tanhf(v);
            }
    }
}

// ---------------------------------------------------------------------------
// Fused z_t dot + single-pass softmax over lo (row resident in registers)
// ---------------------------------------------------------------------------
__global__ __launch_bounds__(256) void out_softmax(
    const float* __restrict__ lo, const float* __restrict__ attn_w,
    const float* __restrict__ z2, const float* __restrict__ W3,
    const float* __restrict__ b3, float* __restrict__ pt)
{
    int b = blockIdx.x, tid = threadIdx.x;
    __shared__ float red[256];

    // z_t = sigmoid(z2[b] . W3 + b3)
    float a = 0.0f;
    for (int k = tid; k < H_SZ; k += 256) a += z2[(size_t)b * H_SZ + k] * W3[k];
    red[tid] = a; __syncthreads();
    for (int s = 128; s > 0; s >>= 1) { if (tid < s) red[tid] += red[tid + s]; __syncthreads(); }
    float zt = 1.0f / (1.0f + expf(-(red[0] + b3[0])));
    __syncthreads();

    float lv[8];
    float mx = -1e30f;
#pragma unroll
    for (int j = 0; j < 8; ++j) {
        int o = j * 256 + tid;
        lv[j] = (o < O_SZ) ? lo[(size_t)b * O_SZ + o] : -1e30f;
        mx = fmaxf(mx, lv[j]);
    }
    red[tid] = mx; __syncthreads();
    for (int s = 128; s > 0; s >>= 1) { if (tid < s) red[tid] = fmaxf(red[tid], red[tid + s]); __syncthreads(); }
    mx = red[0]; __syncthreads();

    float sm = 0.0f;
#pragma unroll
    for (int j = 0; j < 8; ++j) {
        lv[j] = expf(lv[j] - mx);
        sm += lv[j];
    }
    red[tid] = sm; __syncthreads();
    for (int s = 128; s > 0; s >>= 1) { if (tid < s) red[tid] += red[tid + s]; __syncthreads(); }
    float inv = 1.0f / red[0];

#pragma unroll
    for (int j = 0; j < 8; ++j) {
        int o = j * 256 + tid;
        if (o < O_SZ) pt[(size_t)b * 2104 + o] = logf(lv[j] * inv * zt + 1e-20f);
    }
    for (int l = tid; l < LC_SZ; l += 256)
        pt[(size_t)b * 2104 + O_SZ + l] = logf(attn_w[b * LC_SZ + l] * (1.0f - zt) + 1e-20f);
}

// ---------------------------------------------------------------------------
extern "C" void kernel_launch(void* const* d_in, const int* in_sizes, int n_in,
                              void* d_out, int out_size, void* d_ws, size_t ws_size,
                              hipStream_t stream)
{
    const int*   input   = (const int*)d_in[0];
    const int*   input_d = (const int*)d_in[1];
    const float* hidden  = (const float*)d_in[2];
    const float* annot   = (const float*)d_in[3];
    const float* ans     = (const float*)d_in[4];
    const float* emb_w   = (const float*)d_in[5];
    const float* emb_d_w = (const float*)d_in[6];
    const float* attn_W  = (const float*)d_in[7];
    const float* attn_b  = (const float*)d_in[8];
    const float* W_ih    = (const float*)d_in[9];
    const float* W_hh    = (const float*)d_in[10];
    const float* b_ih    = (const float*)d_in[11];
    const float* b_hh    = (const float*)d_in[12];
    const float* mlp_W   = (const float*)d_in[13];
    const float* mlp_b   = (const float*)d_in[14];
    const float* out_W   = (const float*)d_in[15];
    const float* out_b   = (const float*)d_in[16];
    const float* zt_W1   = (const float*)d_in[17];
    const float* zt_b1   = (const float*)d_in[18];
    const float* zt_W2   = (const float*)d_in[19];
    const float* zt_b2   = (const float*)d_in[20];
    const float* zt_W3   = (const float*)d_in[21];
    const float* zt_b3   = (const float*)d_in[22];

    char* p = (char*)d_ws;
    unsigned short* attnWh_bf = (unsigned short*)p; p += (size_t)100 * HK * 2;      //    268,800
    unsigned short* attnWn_bf = (unsigned short*)p; p += (size_t)100 * NK * 2;      // 10,240,000
    unsigned short* Wih_bf    = (unsigned short*)p; p += (size_t)1536 * GIK * 2;    //  4,079,616
    unsigned short* Whh_bf    = (unsigned short*)p; p += (size_t)1536 * 512 * 2;    //  1,572,864
    unsigned short* mlpW_bf   = (unsigned short*)p; p += (size_t)512 * XK * 2;      //  1,884,160
    unsigned short* outW_bf   = (unsigned short*)p; p += (size_t)2004 * 512 * 2;    //  2,052,096
    unsigned short* ztW1_bf   = (unsigned short*)p; p += (size_t)1024 * XK * 2;     //  3,768,320
    unsigned short* ztW2_bf   = (unsigned short*)p; p += (size_t)512 * 1024 * 2;    //  1,048,576
    unsigned short* Ahead     = (unsigned short*)p; p += (size_t)512 * HK * 2;      //  1,376,256
    unsigned short* xm_bf     = (unsigned short*)p; p += (size_t)512 * XK * 2;      //  1,884,160
    unsigned short* et_bf     = (unsigned short*)p; p += (size_t)512 * 512 * 2;     //    524,288
    unsigned short* z1_bf     = (unsigned short*)p; p += (size_t)512 * 1024 * 2;    //  1,048,576
    float* partial = (float*)p; p += (size_t)NSLICE * B_SZ * LC_SZ * 4;             // 17,817,600
    float* attn_w  = (float*)p; p += (size_t)B_SZ * LC_SZ * 4;                      //    204,800
    float* gi      = (float*)p; p += (size_t)512 * 1536 * 4;                        //  3,145,728
    float* gh      = (float*)p; p += (size_t)512 * 1536 * 4;                        //  3,145,728
    float* lo      = (float*)p; p += (size_t)512 * O_SZ * 4;                        //  4,104,192
    float* z2      = (float*)p; p += (size_t)512 * 512 * 4;                         // total ~59 MB

    float* out = (float*)d_out;

    cvt_build<<<CVT_BLKS + 2688, 256, 0, stream>>>(
        attn_W, W_ih, W_hh, mlp_W, out_W, zt_W1, zt_W2,
        attnWh_bf, attnWn_bf, Wih_bf, Whh_bf, mlpW_bf, outW_bf, ztW1_bf, ztW2_bf,
        input, input_d, hidden, ans, emb_w, emb_d_w, Ahead, xm_bf);
    attn_gemm<<<696, 512, 0, stream>>>(annot, Ahead, attnWn_bf, attnWh_bf, partial);
    attn_reduce_softmax<<<512, 128, 0, stream>>>(partial, attn_b, attn_w);
    attn_ct<<<dim3(B_SZ, 2), 256, 0, stream>>>(attn_w, annot, xm_bf);
    gigh_gemm<<<dim3(8, 48), 256, 0, stream>>>(xm_bf, Ahead, Wih_bf, Whh_bf, b_ih, b_hh, gi, gh);
    gru_kernel<<<1024, 256, 0, stream>>>(gi, gh, hidden, xm_bf, out);
    tail1_gemm<<<dim3(8, 24), 256, 0, stream>>>(xm_bf, mlpW_bf, ztW1_bf, mlp_b, zt_b1, et_bf, z1_bf);
    tail2_gemm<<<dim3(8, 40), 256, 0, stream>>>(et_bf, z1_bf, outW_bf, ztW2_bf, out_b, zt_b2, lo, z2);
    out_softmax<<<512, 256, 0, stream>>>(lo, attn_w, z2, zt_W3, zt_b3, out + 2 * B_SZ * H_SZ);
}